// Round 6
// baseline (156.035 us; speedup 1.0000x reference)
//
#include <hip/hip_runtime.h>

typedef _Float16 half8  __attribute__((ext_vector_type(8)));
typedef float    f32x4  __attribute__((ext_vector_type(4)));
typedef unsigned short ushort8 __attribute__((ext_vector_type(8)));

__device__ __forceinline__ float clampf(float v, float lo, float hi){
    return fminf(fmaxf(v, lo), hi);
}
__device__ __forceinline__ float b2f(unsigned short u){
    unsigned int x = ((unsigned int)u) << 16;
    return __builtin_bit_cast(float, x);
}
__device__ __forceinline__ unsigned short f2b(float f){
    unsigned int u = __builtin_bit_cast(unsigned int, f);
    u += 0x7FFFu + ((u >> 16) & 1u);       // round-to-nearest-even
    return (unsigned short)(u >> 16);
}
// raw v_exp_f32 (args bounded |x|<=~80 -> OCML safe path unnecessary)
__device__ __forceinline__ float fexp2(float x){ return __builtin_amdgcn_exp2f(x); }

// async global->LDS staging, 16B/lane (GEMMs only).
__device__ __forceinline__ void gld_lds16(const _Float16* g, _Float16* lds_uniform){
    __builtin_amdgcn_global_load_lds(
        (const __attribute__((address_space(1))) void*)g,
        (__attribute__((address_space(3))) void*)lds_uniform, 16, 0, 0);
}

// ---------------------------------------------------------------------------
// ws layout in _Float16 ELEMENT offsets (all tensors stored as integer-valued f16)
#define EW_WALL 0u                       // [1536][512] packed Wq/Wk/Wv rows
#define EW_WO   786432u                  // [512][512]
#define EW_AQ   1048576u                 // [8192][512] act for q-proj
#define EW_AK   (EW_AQ + 4194304u)
#define EW_AV   (EW_AK + 4194304u)
#define EW_Q    (EW_AV + 4194304u)       // [bh=32][s=2048][d=64]
#define EW_K    (EW_Q  + 4194304u)       // [bh][s][d]
#define EW_VT   (EW_K  + 4194304u)       // [bh][d=64][s=2048]  (V transposed)
#define EW_O    (EW_VT + 4194304u)       // [8192][512]
// total = 30,408,704 elements = 60,817,408 bytes

// ---------------------------------------------------------------------------
// Merged quantization: blocks 0..511 quantize the 4 weight matrices,
// blocks 512..2559 quantize hs into aq/ak/av (saves one launch).
__global__ __launch_bounds__(256) void k_quant(
    const unsigned short* __restrict__ hs,
    const unsigned short* __restrict__ Wq, const unsigned short* __restrict__ Wk,
    const unsigned short* __restrict__ Wv, const unsigned short* __restrict__ Wo,
    _Float16* __restrict__ w_all, _Float16* __restrict__ wo16,
    _Float16* __restrict__ aq, _Float16* __restrict__ ak, _Float16* __restrict__ av,
    const unsigned short* __restrict__ scu)
{
    int blk = blockIdx.x;
    if (blk < 512){
        int gid  = blk * 256 + threadIdx.x;          // 131072 threads, 8 elems
        int idx8 = gid * 8;
        int which = idx8 >> 18;                      // 262144 elems per matrix
        int rem   = idx8 & 262143;
        const unsigned short* W = (which==0)? Wq : (which==1)? Wk : (which==2)? Wv : Wo;
        float sw = b2f((which<3) ? scu[2 + 2*which] : scu[13]);
        ushort8 w = *(const ushort8*)(W + rem);
        half8 o;
        #pragma unroll
        for (int j=0;j<8;j++)
            o[j] = (_Float16)rintf(clampf(b2f(w[j])/sw, -128.f, 127.f));
        _Float16* dst = (which<3) ? (w_all + which*262144 + rem) : (wo16 + rem);
        *(half8*)dst = o;
    } else {
        int gid = (blk - 512) * 256 + threadIdx.x;   // 524288 threads, 8 elems
        int i8 = gid * 8;
        float s0 = b2f(scu[0]), s1 = b2f(scu[1]), s3 = b2f(scu[3]), s5 = b2f(scu[5]);
        ushort8 h = *(const ushort8*)(hs + i8);
        half8 q, k, v;
        #pragma unroll
        for (int j=0;j<8;j++){
            float h1 = rintf(clampf(b2f(h[j])/s0, -128.f, 127.f)) * s0;  // fq(hs,s0)
            q[j] = (_Float16)rintf(clampf(h1/s1, -128.f, 127.f));
            k[j] = (_Float16)rintf(clampf(h1/s3, -128.f, 127.f));
            v[j] = (_Float16)rintf(clampf(h1/s5, -128.f, 127.f));
        }
        *(half8*)(aq+i8) = q;
        *(half8*)(ak+i8) = k;
        *(half8*)(av+i8) = v;
    }
}

// ---------------------------------------------------------------------------
// QKV projection: M=8192, N=1536, K=512. 128x64 tiles, grid (64,24) = 1536
// blocks = 6 blocks/CU. V (proj==2) epilogue via LDS transpose (coalesced).
// R4 (REVERTED): 128x128 tile / grid 768 = 3 blocks/CU + 33 KB LDS regressed
// +7 us: with K=512 (8 K-steps) latency hiding comes from resident waves;
// halving blocks/CU (6->3) cost more than 2x MFMA-per-staged-byte gained.
// Tile choice is shape-dependent: short-K GEMM wants 128x64 @ 6 blocks/CU.
__global__ __launch_bounds__(256) void k_gemm_qkv(
    const _Float16* __restrict__ aq, const _Float16* __restrict__ ak,
    const _Float16* __restrict__ av, const _Float16* __restrict__ w_all,
    _Float16* __restrict__ q16, _Float16* __restrict__ k16, _Float16* __restrict__ vt16,
    const unsigned short* __restrict__ scu)
{
    __shared__ __align__(16) union SMem {
        struct { _Float16 At[128][64]; _Float16 Bt[64][64]; } ab;
        _Float16 Vt[64][132];            // +4 pad: conflict-free transpose
    } sm;
    int tid = threadIdx.x;
    int m0 = blockIdx.x*128, n0 = blockIdx.y*64;
    int proj = blockIdx.y >> 3;                  // 8 n-blocks of 64 per projection
    const _Float16* Ag = (proj==0)? aq : (proj==1)? ak : av;
    int w = tid>>6, lane = tid&63, l15 = lane&15, quad = lane>>4;
    int wm = w>>1, wn = w&1;
    f32x4 z = {0.f,0.f,0.f,0.f};
    f32x4 acc[4][2];
    #pragma unroll
    for (int i=0;i<4;i++)
      #pragma unroll
      for (int j=0;j<2;j++) acc[i][j] = z;

    for (int k0=0; k0<512; k0+=64){
        #pragma unroll
        for (int it=0; it<4; it++){          // A: 128x64 halves = 1024 x 16B
            int idx = it*256 + tid;
            int row = idx>>3, col = (idx&7)*8;
            int ubase = (it*256 + w*64)*8;   // wave-uniform LDS half-offset
            gld_lds16(Ag + (m0+row)*512 + k0 + col, &sm.ab.At[0][0] + ubase);
        }
        #pragma unroll
        for (int it=0; it<2; it++){          // B: 64x64 halves = 512 x 16B
            int idx = it*256 + tid;
            int row = idx>>3, col = (idx&7)*8;
            int ubase = (it*256 + w*64)*8;
            gld_lds16(w_all + (n0+row)*512 + k0 + col, &sm.ab.Bt[0][0] + ubase);
        }
        __syncthreads();
        half8 af[4][2], bf[2][2];
        #pragma unroll
        for (int mt=0; mt<4; mt++){
            af[mt][0] = *(const half8*)(&sm.ab.At[wm*64+mt*16+l15][quad*8]);
            af[mt][1] = *(const half8*)(&sm.ab.At[wm*64+mt*16+l15][32+quad*8]);
        }
        #pragma unroll
        for (int nt=0; nt<2; nt++){
            bf[nt][0] = *(const half8*)(&sm.ab.Bt[wn*32+nt*16+l15][quad*8]);
            bf[nt][1] = *(const half8*)(&sm.ab.Bt[wn*32+nt*16+l15][32+quad*8]);
        }
        #pragma unroll
        for (int mt=0; mt<4; mt++)
          #pragma unroll
          for (int nt=0; nt<2; nt++){
            acc[mt][nt] = __builtin_amdgcn_mfma_f32_16x16x32_f16(af[mt][0], bf[nt][0], acc[mt][nt], 0,0,0);
            acc[mt][nt] = __builtin_amdgcn_mfma_f32_16x16x32_f16(af[mt][1], bf[nt][1], acc[mt][nt], 0,0,0);
          }
        __syncthreads();
    }

    float ssc = b2f(scu[1+2*proj]) * b2f(scu[2+2*proj]);
    float qs  = b2f((proj==0)? scu[7] : (proj==1)? scu[8] : scu[11]);
    if (proj < 2){
        #pragma unroll
        for (int mt=0; mt<4; mt++){
          #pragma unroll
          for (int nt=0; nt<2; nt++){
            int n = n0 + wn*32 + nt*16 + l15;        // C/D col = lane&15 (verified)
            int nloc = n & 511;
            int h = nloc>>6, d = nloc&63;
            #pragma unroll
            for (int r=0;r<4;r++){
              int m = m0 + wm*64 + mt*16 + quad*4 + r;   // C/D row = quad*4+reg
              int b = m>>11, s = m&2047;
              int bh = b*8 + h;
              float val = acc[mt][nt][r] * ssc;
              float qv = rintf(clampf(val/qs, -128.f, 127.f));
              if (proj==0) q16[(bh*2048 + s)*64 + d] = (_Float16)qv;
              else         k16[(bh*2048 + s)*64 + d] = (_Float16)qv;
            }
          }
        }
    } else {
        // stage quantized V-tile into LDS transposed: Vt[n_local][m_local]
        #pragma unroll
        for (int mt=0; mt<4; mt++){
          #pragma unroll
          for (int nt=0; nt<2; nt++){
            int nl = wn*32 + nt*16 + l15;            // n-local 0..63
            #pragma unroll
            for (int r=0;r<4;r++){
              int ml = wm*64 + mt*16 + quad*4 + r;   // m-local 0..127
              float val = acc[mt][nt][r] * ssc;
              sm.Vt[nl][ml] = (_Float16)rintf(clampf(val/qs, -128.f, 127.f));
            }
          }
        }
        __syncthreads();
        int vrow = tid >> 2;                 // 0..63 (n-local)
        int vcol = (tid & 3) * 32;           // m-local base
        int nloc2 = (n0 & 511) + vrow;
        int h2 = nloc2 >> 6, d2 = nloc2 & 63;
        int bh2 = (m0 >> 11)*8 + h2;
        int s2 = (m0 & 2047) + vcol;
        _Float16* dst = vt16 + (bh2*64 + d2)*2048 + s2;
        #pragma unroll
        for (int i=0;i<4;i++)
            *(half8*)(dst + i*8) = *(const half8*)(&sm.Vt[vrow][vcol + i*8]);
    }
}

// ---------------------------------------------------------------------------
// Fused attention. Pass-1 (staged, double-buffered Kbuf) tracks per-chunk
// per-lane max raw scores (cmx[32], unrolled); a provable mask marks chunks
// that can yield nonzero quantized P:
//   needed  iff  any lane: fma(cmx[ch], al2, lml) > -1.0 - 1e-4
// where lml = max over THIS lane's 4 rows of lq9 (monotone chain:
// exp2(x)<=0.5 -> rint(p/s9)=0; per-lane pairing is sound because a lane's
// scores only ever pair with its own rows' lq9 — tighter than wave-max,
// and needs no shuffles). Skipped chunks provably all-zero — bit-identical.
// Pass 2: barrier-free masked loop with direct-global K reads (L2-hot).
// Lessons ledger:
//  R16: (256,6) -> ~240 MB scratch spill. R0: (256,5) caps ~96 unified regs
//   -> cmx spills ~34 MB; grid = 1024 blocks = 4 blocks/CU so >4 waves/SIMD
//   unreachable -> (256,4) is the floor.
//  R2 (REVERTED): direct-global pass-1 K reads: 128 us (2.7x worse) — every
//   wave re-reads the full 8 KB chunk and 4 waves/SIMD can't hide L2
//   latency. LDS staging + 1 barrier/chunk is the cheaper structure.
//  R3 (kept, ~7 us): ballot mask, tree-max, pass-2 row-bound early-out.
//  R5 (REVERTED): distance-2 prefetch neutral/-1us — staging latency was
//   already hidden; deeper prefetch just costs 16 VGPR. Distance-1 is right.
//  R6: grid role swap — bh = blockIdx.x so XCD = linear_id%8 = bh%8: all 32
//   q-blocks sharing one bh's K/V (512 KB) land on ONE XCD -> 4 bh = 2 MB
//   K+V resident per 4 MB L2 (was: scattered, ~8 MB/XCD working set,
//   pass-2 re-reads missed L2 -> 37 MB FETCH vs 25.2 ideal).
__global__ __launch_bounds__(256, 4) void k_attn(
    const _Float16* __restrict__ q16, const _Float16* __restrict__ k16,
    const _Float16* __restrict__ vt16, _Float16* __restrict__ o16,
    const unsigned short* __restrict__ scu)
{
    __shared__ __align__(16) _Float16 Kbuf[2][64][72];   // +8 pad (b128-aligned rows)
    __shared__ __align__(16) _Float16 p16[4][16][72];    // per-wave P staging
    int tid = threadIdx.x;
    int w = tid>>6, lane = tid&63, l15 = lane&15, quad = lane>>4;
    int bh = blockIdx.x;                     // R6: bh on x -> XCD = bh%8
    int q0 = blockIdx.y*64 + w*16;
    float s9 = b2f(scu[9]), s10 = b2f(scu[10]);
    float al2 = b2f(scu[7]) * b2f(scu[8]) * 0.125f * 1.44269504088896341f;

    f32x4 z = {0.f,0.f,0.f,0.f};
    const _Float16* qr = q16 + (bh*2048 + q0 + l15)*64;
    half8 aq0 = *(const half8*)(qr + quad*8);
    half8 aq1 = *(const half8*)(qr + 32 + quad*8);

    const _Float16* kg    = k16  + bh*131072;
    const _Float16* vbase = vt16 + bh*131072;
    int srow = tid>>3, scol = (tid&7)*8;

    half8 kst[2];
    #pragma unroll
    for (int i=0;i<2;i++) kst[i] = *(const half8*)(kg + i*2048 + tid*8);  // chunk 0

    float l[4] = {0.f, 0.f, 0.f, 0.f};
    float cmx[32];                           // per-chunk per-lane max raw score

    // ---- pass 1: denominator sums + per-chunk maxima (UNROLLED: cmx regs) ----
    #pragma unroll
    for (int ch=0; ch<32; ch++){
        int buf = ch & 1;
        #pragma unroll
        for (int i=0;i<2;i++) *(half8*)(&Kbuf[buf][srow + i*32][scol]) = kst[i];
        __syncthreads();
        if (ch < 31){                        // prefetch after barrier
            const _Float16* nsrc = kg + (ch+1)*4096;
            #pragma unroll
            for (int i=0;i<2;i++) kst[i] = *(const half8*)(nsrc + i*2048 + tid*8);
        }
        f32x4 s[4];
        #pragma unroll
        for (int j=0;j<4;j++){
            half8 bk0 = *(const half8*)(&Kbuf[buf][j*16+l15][quad*8]);
            half8 bk1 = *(const half8*)(&Kbuf[buf][j*16+l15][32+quad*8]);
            f32x4 t = __builtin_amdgcn_mfma_f32_16x16x32_f16(aq0, bk0, z, 0,0,0);
            s[j]    = __builtin_amdgcn_mfma_f32_16x16x32_f16(aq1, bk1, t, 0,0,0);
        }
        // tree-max (v_max3-fusable), shallow dependency chain
        float mj[4];
        #pragma unroll
        for (int j=0;j<4;j++){
            mj[j] = fmaxf(fmaxf(s[j][0], s[j][1]), fmaxf(s[j][2], s[j][3]));
            #pragma unroll
            for (int r=0;r<4;r++)
                l[r] += fexp2(s[j][r]*al2);
        }
        cmx[ch] = fmaxf(fmaxf(mj[0], mj[1]), fmaxf(mj[2], mj[3]));
    }

    #pragma unroll
    for (int r=0;r<4;r++){
        #pragma unroll
        for (int d=1; d<16; d<<=1)
            l[r] += __shfl_xor(l[r], d, 64);
    }
    float inv_s9 = 1.0f / s9;
    float r910   = s9 / s10;
    float lq9[4];
    #pragma unroll
    for (int r=0;r<4;r++) lq9[r] = log2f(inv_s9 / l[r]);
    // per-lane threshold: max of THIS lane's rows' lq9 (no shuffles; tighter
    // than the old wave-max since a lane's scores pair only with its rows)
    float lml = fmaxf(fmaxf(lq9[0], lq9[1]), fmaxf(lq9[2], lq9[3]));
    // per-chunk needed mask: any-lane-over-threshold (ballot)
    unsigned int mask = 0u;
    #pragma unroll
    for (int ch=0; ch<32; ch++){
        if (__ballot(fmaf(cmx[ch], al2, lml) > -1.0001f)) mask |= (1u << ch);
    }

    // ---- pass 2: only masked chunks; direct global K loads; no barriers ----
    f32x4 oacc[4];
    #pragma unroll
    for (int dt=0; dt<4; dt++) oacc[dt] = z;
    for (int ch=0; ch<32; ch++){
        if (!(mask & (1u << ch))) continue;
        const _Float16* kc = kg + ch*4096;
        f32x4 s[4];
        #pragma unroll
        for (int j=0;j<4;j++){
            const _Float16* kr = kc + (j*16+l15)*64;
            half8 bk0 = *(const half8*)(kr + quad*8);
            half8 bk1 = *(const half8*)(kr + 32 + quad*8);
            f32x4 t = __builtin_amdgcn_mfma_f32_16x16x32_f16(aq0, bk0, z, 0,0,0);
            s[j]    = __builtin_amdgcn_mfma_f32_16x16x32_f16(aq1, bk1, t, 0,0,0);
        }
        // per-row bound early-out: chunk can contribute only if some row r has
        // max_j s[j][r]*al2 + lq9[r] > -1 (same monotone argument as the mask,
        // but with the row's own lq9 — tighter than the wave-level bound).
        float rmax[4];
        #pragma unroll
        for (int r=0;r<4;r++)
            rmax[r] = fmaxf(fmaxf(s[0][r], s[1][r]), fmaxf(s[2][r], s[3][r]));
        float rb = fmaxf(fmaxf(fmaf(rmax[0], al2, lq9[0]), fmaf(rmax[1], al2, lq9[1])),
                         fmaxf(fmaf(rmax[2], al2, lq9[2]), fmaf(rmax[3], al2, lq9[3])));
        if (!__ballot(rb > -1.0001f)) continue;

        float av[4][4];
        float amax = 0.f;
        #pragma unroll
        for (int j=0;j<4;j++){
            #pragma unroll
            for (int r=0;r<4;r++){
                float p1i = rintf(fminf(fexp2(fmaf(s[j][r], al2, lq9[r])), 255.f));
                float a   = rintf(fminf(p1i*r910, 127.f));
                av[j][r] = a;
                amax = fmaxf(amax, a);
            }
        }
        if (__ballot(amax > 0.f)){           // bound not tight: exact re-check
            #pragma unroll
            for (int j=0;j<4;j++)
                #pragma unroll
                for (int r=0;r<4;r++)
                    p16[w][quad*4+r][j*16+l15] = (_Float16)av[j][r];
            half8 ap0 = *(const half8*)(&p16[w][l15][quad*8]);
            half8 ap1 = *(const half8*)(&p16[w][l15][32+quad*8]);
            #pragma unroll
            for (int dt=0; dt<4; dt++){
                const _Float16* vr0 = vbase + (dt*16+l15)*2048 + ch*64;
                half8 b0 = *(const half8*)(vr0 + quad*8);
                half8 b1 = *(const half8*)(vr0 + 32 + quad*8);
                oacc[dt] = __builtin_amdgcn_mfma_f32_16x16x32_f16(ap0, b0, oacc[dt], 0,0,0);
                oacc[dt] = __builtin_amdgcn_mfma_f32_16x16x32_f16(ap1, b1, oacc[dt], 0,0,0);
            }
        }
    }

    // ---- epilogue: quantize with sc12, direct C-layout stores ----
    float s1011 = b2f(scu[10]) * b2f(scu[11]);
    float s12   = b2f(scu[12]);
    int b = bh>>3, h = bh&7;
    #pragma unroll
    for (int dt=0; dt<4; dt++){
        #pragma unroll
        for (int r=0;r<4;r++){
            float o = oacc[dt][r] * s1011;
            _Float16 v = (_Float16)rintf(clampf(o/s12, -128.f, 127.f));
            o16[(b*2048 + q0 + quad*4 + r)*512 + h*64 + dt*16 + l15] = v;
        }
    }
}

// ---------------------------------------------------------------------------
// Output projection: M=8192, N=512, K=512, + bias, bf16 out. 64x64 tiles.
__global__ __launch_bounds__(256) void k_gemm_out(
    const _Float16* __restrict__ o16, const _Float16* __restrict__ wo16,
    const unsigned short* __restrict__ bo, unsigned short* __restrict__ out,
    const unsigned short* __restrict__ scu)
{
    __shared__ __align__(16) _Float16 At[64][64];
    __shared__ __align__(16) _Float16 Bt[64][64];
    int tid = threadIdx.x;
    int m0 = blockIdx.x*64, n0 = blockIdx.y*64;
    int w = tid>>6, lane = tid&63, l15 = lane&15, quad = lane>>4;
    int wm = w>>1, wn = w&1;
    f32x4 z = {0.f,0.f,0.f,0.f};
    f32x4 acc[2][2];
    #pragma unroll
    for (int i=0;i<2;i++)
      #pragma unroll
      for (int j=0;j<2;j++) acc[i][j] = z;

    for (int k0=0; k0<512; k0+=64){
        #pragma unroll
        for (int it=0; it<2; it++){
            int idx = it*256 + tid;
            int row = idx>>3, col = (idx&7)*8;
            int ubase = (it*256 + w*64)*8;
            gld_lds16(o16  + (m0+row)*512 + k0 + col, &At[0][0] + ubase);
        }
        #pragma unroll
        for (int it=0; it<2; it++){
            int idx = it*256 + tid;
            int row = idx>>3, col = (idx&7)*8;
            int ubase = (it*256 + w*64)*8;
            gld_lds16(wo16 + (n0+row)*512 + k0 + col, &Bt[0][0] + ubase);
        }
        __syncthreads();
        half8 af[2][2], bf[2][2];
        #pragma unroll
        for (int mt=0; mt<2; mt++){
            af[mt][0] = *(const half8*)(&At[wm*32+mt*16+l15][quad*8]);
            af[mt][1] = *(const half8*)(&At[wm*32+mt*16+l15][32+quad*8]);
        }
        #pragma unroll
        for (int nt=0; nt<2; nt++){
            bf[nt][0] = *(const half8*)(&Bt[wn*32+nt*16+l15][quad*8]);
            bf[nt][1] = *(const half8*)(&Bt[wn*32+nt*16+l15][32+quad*8]);
        }
        #pragma unroll
        for (int mt=0; mt<2; mt++)
          #pragma unroll
          for (int nt=0; nt<2; nt++){
            acc[mt][nt] = __builtin_amdgcn_mfma_f32_16x16x32_f16(af[mt][0], bf[nt][0], acc[mt][nt], 0,0,0);
            acc[mt][nt] = __builtin_amdgcn_mfma_f32_16x16x32_f16(af[mt][1], bf[nt][1], acc[mt][nt], 0,0,0);
          }
        __syncthreads();
    }

    float ssc = b2f(scu[12]) * b2f(scu[13]);
    #pragma unroll
    for (int mt=0; mt<2; mt++){
      #pragma unroll
      for (int nt=0; nt<2; nt++){
        int n = n0 + wn*32 + nt*16 + l15;
        float bn = b2f(bo[n]);
        #pragma unroll
        for (int r=0;r<4;r++){
          int m = m0 + wm*32 + mt*16 + quad*4 + r;
          out[m*512 + n] = f2b(acc[mt][nt][r]*ssc + bn);
        }
      }
    }
}

// ---------------------------------------------------------------------------
extern "C" void kernel_launch(void* const* d_in, const int* in_sizes, int n_in,
                              void* d_out, int out_size, void* d_ws, size_t ws_size,
                              hipStream_t stream)
{
    const unsigned short* hs = (const unsigned short*)d_in[0];
    const unsigned short* Wq = (const unsigned short*)d_in[1];
    const unsigned short* Wk = (const unsigned short*)d_in[2];
    const unsigned short* Wv = (const unsigned short*)d_in[3];
    const unsigned short* Wo = (const unsigned short*)d_in[4];
    const unsigned short* bo = (const unsigned short*)d_in[5];
    const unsigned short* sc = (const unsigned short*)d_in[6];
    unsigned short* out = (unsigned short*)d_out;

    _Float16* wsh   = (_Float16*)d_ws;
    _Float16* w_all = wsh + EW_WALL;
    _Float16* wo16  = wsh + EW_WO;
    _Float16* a_q   = wsh + EW_AQ;
    _Float16* a_k   = wsh + EW_AK;
    _Float16* a_v   = wsh + EW_AV;
    _Float16* q16   = wsh + EW_Q;
    _Float16* k16   = wsh + EW_K;
    _Float16* vt16  = wsh + EW_VT;
    _Float16* o16   = wsh + EW_O;

    k_quant<<<2560, 256, 0, stream>>>(hs, Wq, Wk, Wv, Wo, w_all, wo16,
                                      a_q, a_k, a_v, sc);
    k_gemm_qkv<<<dim3(64,24), 256, 0, stream>>>(a_q, a_k, a_v, w_all, q16, k16, vt16, sc);
    k_attn<<<dim3(32,32), 256, 0, stream>>>(q16, k16, vt16, o16, sc);
    k_gemm_out<<<dim3(128,8), 256, 0, stream>>>(o16, wo16, bo, out, sc);
}

// Round 7
// 154.223 us; speedup vs baseline: 1.0117x; 1.0117x over previous
//
#include <hip/hip_runtime.h>

typedef _Float16 half8  __attribute__((ext_vector_type(8)));
typedef float    f32x4  __attribute__((ext_vector_type(4)));
typedef unsigned short ushort8 __attribute__((ext_vector_type(8)));

__device__ __forceinline__ float clampf(float v, float lo, float hi){
    return fminf(fmaxf(v, lo), hi);
}
__device__ __forceinline__ float b2f(unsigned short u){
    unsigned int x = ((unsigned int)u) << 16;
    return __builtin_bit_cast(float, x);
}
__device__ __forceinline__ unsigned short f2b(float f){
    unsigned int u = __builtin_bit_cast(unsigned int, f);
    u += 0x7FFFu + ((u >> 16) & 1u);       // round-to-nearest-even
    return (unsigned short)(u >> 16);
}
// raw v_exp_f32 (args bounded |x|<=~80 -> OCML safe path unnecessary)
__device__ __forceinline__ float fexp2(float x){ return __builtin_amdgcn_exp2f(x); }

// async global->LDS staging, 16B/lane (GEMMs only).
__device__ __forceinline__ void gld_lds16(const _Float16* g, _Float16* lds_uniform){
    __builtin_amdgcn_global_load_lds(
        (const __attribute__((address_space(1))) void*)g,
        (__attribute__((address_space(3))) void*)lds_uniform, 16, 0, 0);
}

// ---------------------------------------------------------------------------
// ws layout in _Float16 ELEMENT offsets (all tensors stored as integer-valued f16)
#define EW_WALL 0u                       // [1536][512] packed Wq/Wk/Wv rows
#define EW_WO   786432u                  // [512][512]
#define EW_AQ   1048576u                 // [8192][512] act for q-proj
#define EW_AK   (EW_AQ + 4194304u)
#define EW_AV   (EW_AK + 4194304u)
#define EW_Q    (EW_AV + 4194304u)       // [bh=32][s=2048][d=64]
#define EW_K    (EW_Q  + 4194304u)       // [bh][s][d]
#define EW_VT   (EW_K  + 4194304u)       // [bh][d=64][s=2048]  (V transposed)
#define EW_O    (EW_VT + 4194304u)       // [8192][512]
// total = 30,408,704 elements = 60,817,408 bytes

// ---------------------------------------------------------------------------
// Merged quantization: blocks 0..511 quantize the 4 weight matrices,
// blocks 512..2559 quantize hs into aq/ak/av (saves one launch).
__global__ __launch_bounds__(256) void k_quant(
    const unsigned short* __restrict__ hs,
    const unsigned short* __restrict__ Wq, const unsigned short* __restrict__ Wk,
    const unsigned short* __restrict__ Wv, const unsigned short* __restrict__ Wo,
    _Float16* __restrict__ w_all, _Float16* __restrict__ wo16,
    _Float16* __restrict__ aq, _Float16* __restrict__ ak, _Float16* __restrict__ av,
    const unsigned short* __restrict__ scu)
{
    int blk = blockIdx.x;
    if (blk < 512){
        int gid  = blk * 256 + threadIdx.x;          // 131072 threads, 8 elems
        int idx8 = gid * 8;
        int which = idx8 >> 18;                      // 262144 elems per matrix
        int rem   = idx8 & 262143;
        const unsigned short* W = (which==0)? Wq : (which==1)? Wk : (which==2)? Wv : Wo;
        float sw = b2f((which<3) ? scu[2 + 2*which] : scu[13]);
        ushort8 w = *(const ushort8*)(W + rem);
        half8 o;
        #pragma unroll
        for (int j=0;j<8;j++)
            o[j] = (_Float16)rintf(clampf(b2f(w[j])/sw, -128.f, 127.f));
        _Float16* dst = (which<3) ? (w_all + which*262144 + rem) : (wo16 + rem);
        *(half8*)dst = o;
    } else {
        int gid = (blk - 512) * 256 + threadIdx.x;   // 524288 threads, 8 elems
        int i8 = gid * 8;
        float s0 = b2f(scu[0]), s1 = b2f(scu[1]), s3 = b2f(scu[3]), s5 = b2f(scu[5]);
        ushort8 h = *(const ushort8*)(hs + i8);
        half8 q, k, v;
        #pragma unroll
        for (int j=0;j<8;j++){
            float h1 = rintf(clampf(b2f(h[j])/s0, -128.f, 127.f)) * s0;  // fq(hs,s0)
            q[j] = (_Float16)rintf(clampf(h1/s1, -128.f, 127.f));
            k[j] = (_Float16)rintf(clampf(h1/s3, -128.f, 127.f));
            v[j] = (_Float16)rintf(clampf(h1/s5, -128.f, 127.f));
        }
        *(half8*)(aq+i8) = q;
        *(half8*)(ak+i8) = k;
        *(half8*)(av+i8) = v;
    }
}

// ---------------------------------------------------------------------------
// QKV projection: M=8192, N=1536, K=512. 128x64 tiles, grid (64,24) = 1536
// blocks = 6 blocks/CU. V (proj==2) epilogue via LDS transpose (coalesced).
// R4 (REVERTED): 128x128 tile / grid 768 = 3 blocks/CU + 33 KB LDS regressed
// +7 us: with K=512 (8 K-steps) latency hiding comes from resident waves;
// halving blocks/CU (6->3) cost more than 2x MFMA-per-staged-byte gained.
// Tile choice is shape-dependent: short-K GEMM wants 128x64 @ 6 blocks/CU.
__global__ __launch_bounds__(256) void k_gemm_qkv(
    const _Float16* __restrict__ aq, const _Float16* __restrict__ ak,
    const _Float16* __restrict__ av, const _Float16* __restrict__ w_all,
    _Float16* __restrict__ q16, _Float16* __restrict__ k16, _Float16* __restrict__ vt16,
    const unsigned short* __restrict__ scu)
{
    __shared__ __align__(16) union SMem {
        struct { _Float16 At[128][64]; _Float16 Bt[64][64]; } ab;
        _Float16 Vt[64][132];            // +4 pad: conflict-free transpose
    } sm;
    int tid = threadIdx.x;
    int m0 = blockIdx.x*128, n0 = blockIdx.y*64;
    int proj = blockIdx.y >> 3;                  // 8 n-blocks of 64 per projection
    const _Float16* Ag = (proj==0)? aq : (proj==1)? ak : av;
    int w = tid>>6, lane = tid&63, l15 = lane&15, quad = lane>>4;
    int wm = w>>1, wn = w&1;
    f32x4 z = {0.f,0.f,0.f,0.f};
    f32x4 acc[4][2];
    #pragma unroll
    for (int i=0;i<4;i++)
      #pragma unroll
      for (int j=0;j<2;j++) acc[i][j] = z;

    for (int k0=0; k0<512; k0+=64){
        #pragma unroll
        for (int it=0; it<4; it++){          // A: 128x64 halves = 1024 x 16B
            int idx = it*256 + tid;
            int row = idx>>3, col = (idx&7)*8;
            int ubase = (it*256 + w*64)*8;   // wave-uniform LDS half-offset
            gld_lds16(Ag + (m0+row)*512 + k0 + col, &sm.ab.At[0][0] + ubase);
        }
        #pragma unroll
        for (int it=0; it<2; it++){          // B: 64x64 halves = 512 x 16B
            int idx = it*256 + tid;
            int row = idx>>3, col = (idx&7)*8;
            int ubase = (it*256 + w*64)*8;
            gld_lds16(w_all + (n0+row)*512 + k0 + col, &sm.ab.Bt[0][0] + ubase);
        }
        __syncthreads();
        half8 af[4][2], bf[2][2];
        #pragma unroll
        for (int mt=0; mt<4; mt++){
            af[mt][0] = *(const half8*)(&sm.ab.At[wm*64+mt*16+l15][quad*8]);
            af[mt][1] = *(const half8*)(&sm.ab.At[wm*64+mt*16+l15][32+quad*8]);
        }
        #pragma unroll
        for (int nt=0; nt<2; nt++){
            bf[nt][0] = *(const half8*)(&sm.ab.Bt[wn*32+nt*16+l15][quad*8]);
            bf[nt][1] = *(const half8*)(&sm.ab.Bt[wn*32+nt*16+l15][32+quad*8]);
        }
        #pragma unroll
        for (int mt=0; mt<4; mt++)
          #pragma unroll
          for (int nt=0; nt<2; nt++){
            acc[mt][nt] = __builtin_amdgcn_mfma_f32_16x16x32_f16(af[mt][0], bf[nt][0], acc[mt][nt], 0,0,0);
            acc[mt][nt] = __builtin_amdgcn_mfma_f32_16x16x32_f16(af[mt][1], bf[nt][1], acc[mt][nt], 0,0,0);
          }
        __syncthreads();
    }

    float ssc = b2f(scu[1+2*proj]) * b2f(scu[2+2*proj]);
    float qs  = b2f((proj==0)? scu[7] : (proj==1)? scu[8] : scu[11]);
    if (proj < 2){
        #pragma unroll
        for (int mt=0; mt<4; mt++){
          #pragma unroll
          for (int nt=0; nt<2; nt++){
            int n = n0 + wn*32 + nt*16 + l15;        // C/D col = lane&15 (verified)
            int nloc = n & 511;
            int h = nloc>>6, d = nloc&63;
            #pragma unroll
            for (int r=0;r<4;r++){
              int m = m0 + wm*64 + mt*16 + quad*4 + r;   // C/D row = quad*4+reg
              int b = m>>11, s = m&2047;
              int bh = b*8 + h;
              float val = acc[mt][nt][r] * ssc;
              float qv = rintf(clampf(val/qs, -128.f, 127.f));
              if (proj==0) q16[(bh*2048 + s)*64 + d] = (_Float16)qv;
              else         k16[(bh*2048 + s)*64 + d] = (_Float16)qv;
            }
          }
        }
    } else {
        // stage quantized V-tile into LDS transposed: Vt[n_local][m_local]
        #pragma unroll
        for (int mt=0; mt<4; mt++){
          #pragma unroll
          for (int nt=0; nt<2; nt++){
            int nl = wn*32 + nt*16 + l15;            // n-local 0..63
            #pragma unroll
            for (int r=0;r<4;r++){
              int ml = wm*64 + mt*16 + quad*4 + r;   // m-local 0..127
              float val = acc[mt][nt][r] * ssc;
              sm.Vt[nl][ml] = (_Float16)rintf(clampf(val/qs, -128.f, 127.f));
            }
          }
        }
        __syncthreads();
        int vrow = tid >> 2;                 // 0..63 (n-local)
        int vcol = (tid & 3) * 32;           // m-local base
        int nloc2 = (n0 & 511) + vrow;
        int h2 = nloc2 >> 6, d2 = nloc2 & 63;
        int bh2 = (m0 >> 11)*8 + h2;
        int s2 = (m0 & 2047) + vcol;
        _Float16* dst = vt16 + (bh2*64 + d2)*2048 + s2;
        #pragma unroll
        for (int i=0;i<4;i++)
            *(half8*)(dst + i*8) = *(const half8*)(&sm.Vt[vrow][vcol + i*8]);
    }
}

// ---------------------------------------------------------------------------
// Fused attention. Pass-1 (staged, double-buffered Kbuf) tracks per-chunk
// per-lane max raw scores (cmx[32], unrolled); a provable mask marks chunks
// that can yield nonzero quantized P:
//   needed  iff  any lane: fma(cmx[ch], al2, lml) > -1.0 - 1e-4
// where lml = max over THIS lane's 4 rows of lq9 (monotone chain:
// exp2(x)<=0.5 -> rint(p/s9)=0; per-lane pairing sound — a lane's scores
// only pair with its own rows' lq9). Skipped chunks provably all-zero —
// bit-identical. Pass 2: barrier-free masked loop, direct-global K (L2-hot).
// Lessons ledger:
//  R16: (256,6) -> ~240 MB scratch spill. R0: (256,5) caps ~96 unified regs
//   -> cmx spills ~34 MB; 4-waves/SIMD reachable max -> (...,4) is the floor.
//  R2 (REVERTED): direct-global pass-1 K reads: 128 us (2.7x worse) — every
//   wave re-reads the full 8 KB chunk; staging + 1 barrier/chunk is cheaper.
//  R3 (kept, ~7 us): ballot mask, tree-max, pass-2 row-bound early-out.
//  R5 (REVERTED): distance-2 prefetch neutral — staging latency already
//   hidden at 16 waves/CU; distance-1 is right.
//  R6 (kept, neutral): bh on blockIdx.x -> XCD = bh%8 (K/V L2-locality);
//   per-lane lml mask. Did not move time -> attn not L2-bound.
//  R7: 8-wave / 128-q-row blocks (512 thr), grid (32,16) = 512 = 2/CU.
//   Same 16 waves/CU; K-staging amortized over 8 waves: 1 load + 1 ds_write
//   per thread per chunk (was 2+2), pass-1 K L2 traffic halves (268->134 MB).
//   Per-wave compute unchanged — isolates staging-amortization effect.
__global__ __launch_bounds__(512, 4) void k_attn(
    const _Float16* __restrict__ q16, const _Float16* __restrict__ k16,
    const _Float16* __restrict__ vt16, _Float16* __restrict__ o16,
    const unsigned short* __restrict__ scu)
{
    __shared__ __align__(16) _Float16 Kbuf[2][64][72];   // +8 pad (b128-aligned rows)
    __shared__ __align__(16) _Float16 p16[8][16][72];    // per-wave P staging
    int tid = threadIdx.x;
    int w = tid>>6, lane = tid&63, l15 = lane&15, quad = lane>>4;
    int bh = blockIdx.x;                     // XCD = bh%8 (R6)
    int q0 = blockIdx.y*128 + w*16;          // 8 waves cover 128 q-rows
    float s9 = b2f(scu[9]), s10 = b2f(scu[10]);
    float al2 = b2f(scu[7]) * b2f(scu[8]) * 0.125f * 1.44269504088896341f;

    f32x4 z = {0.f,0.f,0.f,0.f};
    const _Float16* qr = q16 + (bh*2048 + q0 + l15)*64;
    half8 aq0 = *(const half8*)(qr + quad*8);
    half8 aq1 = *(const half8*)(qr + 32 + quad*8);

    const _Float16* kg    = k16  + bh*131072;
    const _Float16* vbase = vt16 + bh*131072;
    int srow = tid>>3, scol = (tid&7)*8;     // 512 thr x 16B = one 8 KB chunk

    half8 kst = *(const half8*)(kg + tid*8); // chunk 0

    float l[4] = {0.f, 0.f, 0.f, 0.f};
    float cmx[32];                           // per-chunk per-lane max raw score

    // ---- pass 1: denominator sums + per-chunk maxima (UNROLLED: cmx regs) ----
    #pragma unroll
    for (int ch=0; ch<32; ch++){
        int buf = ch & 1;
        *(half8*)(&Kbuf[buf][srow][scol]) = kst;
        __syncthreads();
        if (ch < 31)                         // distance-1 prefetch after barrier
            kst = *(const half8*)(kg + (ch+1)*4096 + tid*8);
        f32x4 s[4];
        #pragma unroll
        for (int j=0;j<4;j++){
            half8 bk0 = *(const half8*)(&Kbuf[buf][j*16+l15][quad*8]);
            half8 bk1 = *(const half8*)(&Kbuf[buf][j*16+l15][32+quad*8]);
            f32x4 t = __builtin_amdgcn_mfma_f32_16x16x32_f16(aq0, bk0, z, 0,0,0);
            s[j]    = __builtin_amdgcn_mfma_f32_16x16x32_f16(aq1, bk1, t, 0,0,0);
        }
        // tree-max (v_max3-fusable), shallow dependency chain
        float mj[4];
        #pragma unroll
        for (int j=0;j<4;j++){
            mj[j] = fmaxf(fmaxf(s[j][0], s[j][1]), fmaxf(s[j][2], s[j][3]));
            #pragma unroll
            for (int r=0;r<4;r++)
                l[r] += fexp2(s[j][r]*al2);
        }
        cmx[ch] = fmaxf(fmaxf(mj[0], mj[1]), fmaxf(mj[2], mj[3]));
    }

    #pragma unroll
    for (int r=0;r<4;r++){
        #pragma unroll
        for (int d=1; d<16; d<<=1)
            l[r] += __shfl_xor(l[r], d, 64);
    }
    float inv_s9 = 1.0f / s9;
    float r910   = s9 / s10;
    float lq9[4];
    #pragma unroll
    for (int r=0;r<4;r++) lq9[r] = log2f(inv_s9 / l[r]);
    // per-lane threshold: max of THIS lane's rows' lq9 (no shuffles; tighter
    // than wave-max since a lane's scores pair only with its rows)
    float lml = fmaxf(fmaxf(lq9[0], lq9[1]), fmaxf(lq9[2], lq9[3]));
    // per-chunk needed mask: any-lane-over-threshold (ballot)
    unsigned int mask = 0u;
    #pragma unroll
    for (int ch=0; ch<32; ch++){
        if (__ballot(fmaf(cmx[ch], al2, lml) > -1.0001f)) mask |= (1u << ch);
    }

    // ---- pass 2: only masked chunks; direct global K loads; no barriers ----
    f32x4 oacc[4];
    #pragma unroll
    for (int dt=0; dt<4; dt++) oacc[dt] = z;
    for (int ch=0; ch<32; ch++){
        if (!(mask & (1u << ch))) continue;
        const _Float16* kc = kg + ch*4096;
        f32x4 s[4];
        #pragma unroll
        for (int j=0;j<4;j++){
            const _Float16* kr = kc + (j*16+l15)*64;
            half8 bk0 = *(const half8*)(kr + quad*8);
            half8 bk1 = *(const half8*)(kr + 32 + quad*8);
            f32x4 t = __builtin_amdgcn_mfma_f32_16x16x32_f16(aq0, bk0, z, 0,0,0);
            s[j]    = __builtin_amdgcn_mfma_f32_16x16x32_f16(aq1, bk1, t, 0,0,0);
        }
        // per-row bound early-out: chunk can contribute only if some row r has
        // max_j s[j][r]*al2 + lq9[r] > -1 (same monotone argument as the mask,
        // but with the row's own lq9 — tighter than the wave-level bound).
        float rmax[4];
        #pragma unroll
        for (int r=0;r<4;r++)
            rmax[r] = fmaxf(fmaxf(s[0][r], s[1][r]), fmaxf(s[2][r], s[3][r]));
        float rb = fmaxf(fmaxf(fmaf(rmax[0], al2, lq9[0]), fmaf(rmax[1], al2, lq9[1])),
                         fmaxf(fmaf(rmax[2], al2, lq9[2]), fmaf(rmax[3], al2, lq9[3])));
        if (!__ballot(rb > -1.0001f)) continue;

        float av[4][4];
        float amax = 0.f;
        #pragma unroll
        for (int j=0;j<4;j++){
            #pragma unroll
            for (int r=0;r<4;r++){
                float p1i = rintf(fminf(fexp2(fmaf(s[j][r], al2, lq9[r])), 255.f));
                float a   = rintf(fminf(p1i*r910, 127.f));
                av[j][r] = a;
                amax = fmaxf(amax, a);
            }
        }
        if (__ballot(amax > 0.f)){           // bound not tight: exact re-check
            #pragma unroll
            for (int j=0;j<4;j++)
                #pragma unroll
                for (int r=0;r<4;r++)
                    p16[w][quad*4+r][j*16+l15] = (_Float16)av[j][r];
            half8 ap0 = *(const half8*)(&p16[w][l15][quad*8]);
            half8 ap1 = *(const half8*)(&p16[w][l15][32+quad*8]);
            #pragma unroll
            for (int dt=0; dt<4; dt++){
                const _Float16* vr0 = vbase + (dt*16+l15)*2048 + ch*64;
                half8 b0 = *(const half8*)(vr0 + quad*8);
                half8 b1 = *(const half8*)(vr0 + 32 + quad*8);
                oacc[dt] = __builtin_amdgcn_mfma_f32_16x16x32_f16(ap0, b0, oacc[dt], 0,0,0);
                oacc[dt] = __builtin_amdgcn_mfma_f32_16x16x32_f16(ap1, b1, oacc[dt], 0,0,0);
            }
        }
    }

    // ---- epilogue: quantize with sc12, direct C-layout stores ----
    float s1011 = b2f(scu[10]) * b2f(scu[11]);
    float s12   = b2f(scu[12]);
    int b = bh>>3, h = bh&7;
    #pragma unroll
    for (int dt=0; dt<4; dt++){
        #pragma unroll
        for (int r=0;r<4;r++){
            float o = oacc[dt][r] * s1011;
            _Float16 v = (_Float16)rintf(clampf(o/s12, -128.f, 127.f));
            o16[(b*2048 + q0 + quad*4 + r)*512 + h*64 + dt*16 + l15] = v;
        }
    }
}

// ---------------------------------------------------------------------------
// Output projection: M=8192, N=512, K=512, + bias, bf16 out. 64x64 tiles.
__global__ __launch_bounds__(256) void k_gemm_out(
    const _Float16* __restrict__ o16, const _Float16* __restrict__ wo16,
    const unsigned short* __restrict__ bo, unsigned short* __restrict__ out,
    const unsigned short* __restrict__ scu)
{
    __shared__ __align__(16) _Float16 At[64][64];
    __shared__ __align__(16) _Float16 Bt[64][64];
    int tid = threadIdx.x;
    int m0 = blockIdx.x*64, n0 = blockIdx.y*64;
    int w = tid>>6, lane = tid&63, l15 = lane&15, quad = lane>>4;
    int wm = w>>1, wn = w&1;
    f32x4 z = {0.f,0.f,0.f,0.f};
    f32x4 acc[2][2];
    #pragma unroll
    for (int i=0;i<2;i++)
      #pragma unroll
      for (int j=0;j<2;j++) acc[i][j] = z;

    for (int k0=0; k0<512; k0+=64){
        #pragma unroll
        for (int it=0; it<2; it++){
            int idx = it*256 + tid;
            int row = idx>>3, col = (idx&7)*8;
            int ubase = (it*256 + w*64)*8;
            gld_lds16(o16  + (m0+row)*512 + k0 + col, &At[0][0] + ubase);
        }
        #pragma unroll
        for (int it=0; it<2; it++){
            int idx = it*256 + tid;
            int row = idx>>3, col = (idx&7)*8;
            int ubase = (it*256 + w*64)*8;
            gld_lds16(wo16 + (n0+row)*512 + k0 + col, &Bt[0][0] + ubase);
        }
        __syncthreads();
        half8 af[2][2], bf[2][2];
        #pragma unroll
        for (int mt=0; mt<2; mt++){
            af[mt][0] = *(const half8*)(&At[wm*32+mt*16+l15][quad*8]);
            af[mt][1] = *(const half8*)(&At[wm*32+mt*16+l15][32+quad*8]);
        }
        #pragma unroll
        for (int nt=0; nt<2; nt++){
            bf[nt][0] = *(const half8*)(&Bt[wn*32+nt*16+l15][quad*8]);
            bf[nt][1] = *(const half8*)(&Bt[wn*32+nt*16+l15][32+quad*8]);
        }
        #pragma unroll
        for (int mt=0; mt<2; mt++)
          #pragma unroll
          for (int nt=0; nt<2; nt++){
            acc[mt][nt] = __builtin_amdgcn_mfma_f32_16x16x32_f16(af[mt][0], bf[nt][0], acc[mt][nt], 0,0,0);
            acc[mt][nt] = __builtin_amdgcn_mfma_f32_16x16x32_f16(af[mt][1], bf[nt][1], acc[mt][nt], 0,0,0);
          }
        __syncthreads();
    }

    float ssc = b2f(scu[12]) * b2f(scu[13]);
    #pragma unroll
    for (int mt=0; mt<2; mt++){
      #pragma unroll
      for (int nt=0; nt<2; nt++){
        int n = n0 + wn*32 + nt*16 + l15;
        float bn = b2f(bo[n]);
        #pragma unroll
        for (int r=0;r<4;r++){
          int m = m0 + wm*32 + mt*16 + quad*4 + r;
          out[m*512 + n] = f2b(acc[mt][nt][r]*ssc + bn);
        }
      }
    }
}

// ---------------------------------------------------------------------------
extern "C" void kernel_launch(void* const* d_in, const int* in_sizes, int n_in,
                              void* d_out, int out_size, void* d_ws, size_t ws_size,
                              hipStream_t stream)
{
    const unsigned short* hs = (const unsigned short*)d_in[0];
    const unsigned short* Wq = (const unsigned short*)d_in[1];
    const unsigned short* Wk = (const unsigned short*)d_in[2];
    const unsigned short* Wv = (const unsigned short*)d_in[3];
    const unsigned short* Wo = (const unsigned short*)d_in[4];
    const unsigned short* bo = (const unsigned short*)d_in[5];
    const unsigned short* sc = (const unsigned short*)d_in[6];
    unsigned short* out = (unsigned short*)d_out;

    _Float16* wsh   = (_Float16*)d_ws;
    _Float16* w_all = wsh + EW_WALL;
    _Float16* wo16  = wsh + EW_WO;
    _Float16* a_q   = wsh + EW_AQ;
    _Float16* a_k   = wsh + EW_AK;
    _Float16* a_v   = wsh + EW_AV;
    _Float16* q16   = wsh + EW_Q;
    _Float16* k16   = wsh + EW_K;
    _Float16* vt16  = wsh + EW_VT;
    _Float16* o16   = wsh + EW_O;

    k_quant<<<2560, 256, 0, stream>>>(hs, Wq, Wk, Wv, Wo, w_all, wo16,
                                      a_q, a_k, a_v, sc);
    k_gemm_qkv<<<dim3(64,24), 256, 0, stream>>>(a_q, a_k, a_v, w_all, q16, k16, vt16, sc);
    k_attn<<<dim3(32,16), 512, 0, stream>>>(q16, k16, vt16, o16, sc);
    k_gemm_out<<<dim3(128,8), 256, 0, stream>>>(o16, wo16, bo, out, sc);
}

// Round 8
// 144.460 us; speedup vs baseline: 1.0801x; 1.0676x over previous
//
#include <hip/hip_runtime.h>

typedef _Float16 half8  __attribute__((ext_vector_type(8)));
typedef float    f32x4  __attribute__((ext_vector_type(4)));
typedef int      i32x4  __attribute__((ext_vector_type(4)));
typedef unsigned short ushort8 __attribute__((ext_vector_type(8)));
typedef signed char char8 __attribute__((ext_vector_type(8)));

__device__ __forceinline__ float clampf(float v, float lo, float hi){
    return fminf(fmaxf(v, lo), hi);
}
__device__ __forceinline__ float b2f(unsigned short u){
    unsigned int x = ((unsigned int)u) << 16;
    return __builtin_bit_cast(float, x);
}
__device__ __forceinline__ unsigned short f2b(float f){
    unsigned int u = __builtin_bit_cast(unsigned int, f);
    u += 0x7FFFu + ((u >> 16) & 1u);       // round-to-nearest-even
    return (unsigned short)(u >> 16);
}
// raw v_exp_f32 (args bounded |x|<=~80 -> OCML safe path unnecessary)
__device__ __forceinline__ float fexp2(float x){ return __builtin_amdgcn_exp2f(x); }

// async global->LDS staging, 16B/lane.
__device__ __forceinline__ void gld_lds16(const void* g, void* lds_uniform){
    __builtin_amdgcn_global_load_lds(
        (const __attribute__((address_space(1))) void*)g,
        (__attribute__((address_space(3))) void*)lds_uniform, 16, 0, 0);
}

// ---------------------------------------------------------------------------
// ws layout in BYTES. GEMM-side tensors are int8 (R8); attn tensors f16.
#define BW_WALL 0u                        // [1536][512] i8 packed Wq/Wk/Wv rows
#define BW_WO   786432u                   // [512][512] i8
#define BW_AQ   1048576u                  // [8192][512] i8
#define BW_AK   (BW_AQ + 4194304u)
#define BW_AV   (BW_AK + 4194304u)
#define BW_Q    (BW_AV + 4194304u)        // f16 [bh=32][s=2048][d=64]
#define BW_K    (BW_Q  + 8388608u)
#define BW_VT   (BW_K  + 8388608u)        // f16 [bh][d=64][s=2048]
#define BW_O    (BW_VT + 8388608u)        // [8192][512] i8
// total = 42,991,616 bytes

// ---------------------------------------------------------------------------
// Merged quantization -> int8 outputs (R8: GEMMs run i8 MFMA).
__global__ __launch_bounds__(256) void k_quant(
    const unsigned short* __restrict__ hs,
    const unsigned short* __restrict__ Wq, const unsigned short* __restrict__ Wk,
    const unsigned short* __restrict__ Wv, const unsigned short* __restrict__ Wo,
    signed char* __restrict__ w_all, signed char* __restrict__ wo8,
    signed char* __restrict__ aq, signed char* __restrict__ ak,
    signed char* __restrict__ av,
    const unsigned short* __restrict__ scu)
{
    int blk = blockIdx.x;
    if (blk < 512){
        int gid  = blk * 256 + threadIdx.x;          // 131072 threads, 8 elems
        int idx8 = gid * 8;
        int which = idx8 >> 18;                      // 262144 elems per matrix
        int rem   = idx8 & 262143;
        const unsigned short* W = (which==0)? Wq : (which==1)? Wk : (which==2)? Wv : Wo;
        float sw = b2f((which<3) ? scu[2 + 2*which] : scu[13]);
        ushort8 w = *(const ushort8*)(W + rem);
        char8 o;
        #pragma unroll
        for (int j=0;j<8;j++)
            o[j] = (signed char)rintf(clampf(b2f(w[j])/sw, -128.f, 127.f));
        signed char* dst = (which<3) ? (w_all + which*262144 + rem) : (wo8 + rem);
        *(char8*)dst = o;
    } else {
        int gid = (blk - 512) * 256 + threadIdx.x;   // 524288 threads, 8 elems
        int i8 = gid * 8;
        float s0 = b2f(scu[0]), s1 = b2f(scu[1]), s3 = b2f(scu[3]), s5 = b2f(scu[5]);
        ushort8 h = *(const ushort8*)(hs + i8);
        char8 q, k, v;
        #pragma unroll
        for (int j=0;j<8;j++){
            float h1 = rintf(clampf(b2f(h[j])/s0, -128.f, 127.f)) * s0;  // fq(hs,s0)
            q[j] = (signed char)rintf(clampf(h1/s1, -128.f, 127.f));
            k[j] = (signed char)rintf(clampf(h1/s3, -128.f, 127.f));
            v[j] = (signed char)rintf(clampf(h1/s5, -128.f, 127.f));
        }
        *(char8*)(aq+i8) = q;
        *(char8*)(ak+i8) = k;
        *(char8*)(av+i8) = v;
    }
}

// ---------------------------------------------------------------------------
// QKV projection: M=8192, N=1536, K=512. 128x64 tiles, grid (64,24) = 1536
// blocks = 6 blocks/CU. R8: int8 operands + v_mfma_i32_16x16x64_i8 — exact
// (operands are integers in [-128,127]; |acc| <= 8.4M < 2^31). Staging bytes
// halve (A 8KB + B 4KB per K-step), MFMA count halves at 2x MAC rate.
// Fragment layout: lane(row=l15, quad) holds 16 contiguous bytes at
// k = quad*16 — the same contiguous-K-run pattern as the verified f16 path.
// R4 lesson stands: 128x64 @ 6 blocks/CU for this short-K shape.
__global__ __launch_bounds__(256) void k_gemm_qkv(
    const signed char* __restrict__ aq, const signed char* __restrict__ ak,
    const signed char* __restrict__ av, const signed char* __restrict__ w_all,
    _Float16* __restrict__ q16, _Float16* __restrict__ k16, _Float16* __restrict__ vt16,
    const unsigned short* __restrict__ scu)
{
    __shared__ __align__(16) union SMem {
        struct { signed char At[128][64]; signed char Bt[64][64]; } ab;
        _Float16 Vt[64][132];            // +4 pad: conflict-free transpose
    } sm;
    int tid = threadIdx.x;
    int m0 = blockIdx.x*128, n0 = blockIdx.y*64;
    int proj = blockIdx.y >> 3;                  // 8 n-blocks of 64 per projection
    const signed char* Ag = (proj==0)? aq : (proj==1)? ak : av;
    int w = tid>>6, lane = tid&63, l15 = lane&15, quad = lane>>4;
    int wm = w>>1, wn = w&1;
    i32x4 z = {0,0,0,0};
    i32x4 acc[4][2];
    #pragma unroll
    for (int i=0;i<4;i++)
      #pragma unroll
      for (int j=0;j<2;j++) acc[i][j] = z;

    for (int k0=0; k0<512; k0+=64){
        #pragma unroll
        for (int it=0; it<2; it++){          // A: 128x64 bytes = 512 x 16B
            int idx = it*256 + tid;
            int row = idx>>2, col = (idx&3)*16;
            int ubase = (it*256 + w*64)*16;  // wave-uniform LDS byte offset
            gld_lds16(Ag + (m0+row)*512 + k0 + col, &sm.ab.At[0][0] + ubase);
        }
        {                                    // B: 64x64 bytes = 256 x 16B
            int row = tid>>2, col = (tid&3)*16;
            int ubase = (w*64)*16;
            gld_lds16(w_all + (n0+row)*512 + k0 + col, &sm.ab.Bt[0][0] + ubase);
        }
        __syncthreads();
        i32x4 af[4], bf[2];
        #pragma unroll
        for (int mt=0; mt<4; mt++)
            af[mt] = *(const i32x4*)(&sm.ab.At[wm*64+mt*16+l15][quad*16]);
        #pragma unroll
        for (int nt=0; nt<2; nt++)
            bf[nt] = *(const i32x4*)(&sm.ab.Bt[wn*32+nt*16+l15][quad*16]);
        #pragma unroll
        for (int mt=0; mt<4; mt++)
          #pragma unroll
          for (int nt=0; nt<2; nt++)
            acc[mt][nt] = __builtin_amdgcn_mfma_i32_16x16x64_i8(af[mt], bf[nt], acc[mt][nt], 0,0,0);
        __syncthreads();
    }

    float ssc = b2f(scu[1+2*proj]) * b2f(scu[2+2*proj]);
    float qs  = b2f((proj==0)? scu[7] : (proj==1)? scu[8] : scu[11]);
    if (proj < 2){
        #pragma unroll
        for (int mt=0; mt<4; mt++){
          #pragma unroll
          for (int nt=0; nt<2; nt++){
            int n = n0 + wn*32 + nt*16 + l15;        // C/D col = lane&15 (verified)
            int nloc = n & 511;
            int h = nloc>>6, d = nloc&63;
            #pragma unroll
            for (int r=0;r<4;r++){
              int m = m0 + wm*64 + mt*16 + quad*4 + r;   // C/D row = quad*4+reg
              int b = m>>11, s = m&2047;
              int bh = b*8 + h;
              float val = (float)acc[mt][nt][r] * ssc;
              float qv = rintf(clampf(val/qs, -128.f, 127.f));
              if (proj==0) q16[(bh*2048 + s)*64 + d] = (_Float16)qv;
              else         k16[(bh*2048 + s)*64 + d] = (_Float16)qv;
            }
          }
        }
    } else {
        // stage quantized V-tile into LDS transposed: Vt[n_local][m_local]
        #pragma unroll
        for (int mt=0; mt<4; mt++){
          #pragma unroll
          for (int nt=0; nt<2; nt++){
            int nl = wn*32 + nt*16 + l15;            // n-local 0..63
            #pragma unroll
            for (int r=0;r<4;r++){
              int ml = wm*64 + mt*16 + quad*4 + r;   // m-local 0..127
              float val = (float)acc[mt][nt][r] * ssc;
              sm.Vt[nl][ml] = (_Float16)rintf(clampf(val/qs, -128.f, 127.f));
            }
          }
        }
        __syncthreads();
        int vrow = tid >> 2;                 // 0..63 (n-local)
        int vcol = (tid & 3) * 32;           // m-local base
        int nloc2 = (n0 & 511) + vrow;
        int h2 = nloc2 >> 6, d2 = nloc2 & 63;
        int bh2 = (m0 >> 11)*8 + h2;
        int s2 = (m0 & 2047) + vcol;
        _Float16* dst = vt16 + (bh2*64 + d2)*2048 + s2;
        #pragma unroll
        for (int i=0;i<4;i++)
            *(half8*)(dst + i*8) = *(const half8*)(&sm.Vt[vrow][vcol + i*8]);
    }
}

// ---------------------------------------------------------------------------
// Fused attention (R7 structure: 8 waves / 128 q-rows, grid (32,16)).
// Pass-1 (staged, double-buffered Kbuf) + provable chunk mask + pass-2
// masked loop. Bit-identical skipping (monotone exp2/rint chain).
// Lessons ledger: R2 staging removal REVERTED (2.7x worse); R5 distance-2
// prefetch REVERTED (neutral); R3 VALU diet kept (~7us); R6 bh->blockIdx.x
// XCD locality kept (neutral); R7 8-wave staging kept (neutral, less L2).
// R8: epilogue stores o as int8 (value already integer in [-128,127]) for
// the i8 output GEMM. Everything else untouched.
__global__ __launch_bounds__(512, 4) void k_attn(
    const _Float16* __restrict__ q16, const _Float16* __restrict__ k16,
    const _Float16* __restrict__ vt16, signed char* __restrict__ o8,
    const unsigned short* __restrict__ scu)
{
    __shared__ __align__(16) _Float16 Kbuf[2][64][72];   // +8 pad (b128-aligned rows)
    __shared__ __align__(16) _Float16 p16[8][16][72];    // per-wave P staging
    int tid = threadIdx.x;
    int w = tid>>6, lane = tid&63, l15 = lane&15, quad = lane>>4;
    int bh = blockIdx.x;                     // XCD = bh%8 (R6)
    int q0 = blockIdx.y*128 + w*16;          // 8 waves cover 128 q-rows
    float s9 = b2f(scu[9]), s10 = b2f(scu[10]);
    float al2 = b2f(scu[7]) * b2f(scu[8]) * 0.125f * 1.44269504088896341f;

    f32x4 z = {0.f,0.f,0.f,0.f};
    const _Float16* qr = q16 + (bh*2048 + q0 + l15)*64;
    half8 aq0 = *(const half8*)(qr + quad*8);
    half8 aq1 = *(const half8*)(qr + 32 + quad*8);

    const _Float16* kg    = k16  + bh*131072;
    const _Float16* vbase = vt16 + bh*131072;
    int srow = tid>>3, scol = (tid&7)*8;     // 512 thr x 16B = one 8 KB chunk

    half8 kst = *(const half8*)(kg + tid*8); // chunk 0

    float l[4] = {0.f, 0.f, 0.f, 0.f};
    float cmx[32];                           // per-chunk per-lane max raw score

    // ---- pass 1: denominator sums + per-chunk maxima (UNROLLED: cmx regs) ----
    #pragma unroll
    for (int ch=0; ch<32; ch++){
        int buf = ch & 1;
        *(half8*)(&Kbuf[buf][srow][scol]) = kst;
        __syncthreads();
        if (ch < 31)                         // distance-1 prefetch after barrier
            kst = *(const half8*)(kg + (ch+1)*4096 + tid*8);
        f32x4 s[4];
        #pragma unroll
        for (int j=0;j<4;j++){
            half8 bk0 = *(const half8*)(&Kbuf[buf][j*16+l15][quad*8]);
            half8 bk1 = *(const half8*)(&Kbuf[buf][j*16+l15][32+quad*8]);
            f32x4 t = __builtin_amdgcn_mfma_f32_16x16x32_f16(aq0, bk0, z, 0,0,0);
            s[j]    = __builtin_amdgcn_mfma_f32_16x16x32_f16(aq1, bk1, t, 0,0,0);
        }
        // tree-max (v_max3-fusable), shallow dependency chain
        float mj[4];
        #pragma unroll
        for (int j=0;j<4;j++){
            mj[j] = fmaxf(fmaxf(s[j][0], s[j][1]), fmaxf(s[j][2], s[j][3]));
            #pragma unroll
            for (int r=0;r<4;r++)
                l[r] += fexp2(s[j][r]*al2);
        }
        cmx[ch] = fmaxf(fmaxf(mj[0], mj[1]), fmaxf(mj[2], mj[3]));
    }

    #pragma unroll
    for (int r=0;r<4;r++){
        #pragma unroll
        for (int d=1; d<16; d<<=1)
            l[r] += __shfl_xor(l[r], d, 64);
    }
    float inv_s9 = 1.0f / s9;
    float r910   = s9 / s10;
    float lq9[4];
    #pragma unroll
    for (int r=0;r<4;r++) lq9[r] = log2f(inv_s9 / l[r]);
    // per-lane threshold: max of THIS lane's rows' lq9 (no shuffles; tighter
    // than wave-max since a lane's scores pair only with its rows)
    float lml = fmaxf(fmaxf(lq9[0], lq9[1]), fmaxf(lq9[2], lq9[3]));
    // per-chunk needed mask: any-lane-over-threshold (ballot)
    unsigned int mask = 0u;
    #pragma unroll
    for (int ch=0; ch<32; ch++){
        if (__ballot(fmaf(cmx[ch], al2, lml) > -1.0001f)) mask |= (1u << ch);
    }

    // ---- pass 2: only masked chunks; direct global K loads; no barriers ----
    f32x4 oacc[4];
    #pragma unroll
    for (int dt=0; dt<4; dt++) oacc[dt] = z;
    for (int ch=0; ch<32; ch++){
        if (!(mask & (1u << ch))) continue;
        const _Float16* kc = kg + ch*4096;
        f32x4 s[4];
        #pragma unroll
        for (int j=0;j<4;j++){
            const _Float16* kr = kc + (j*16+l15)*64;
            half8 bk0 = *(const half8*)(kr + quad*8);
            half8 bk1 = *(const half8*)(kr + 32 + quad*8);
            f32x4 t = __builtin_amdgcn_mfma_f32_16x16x32_f16(aq0, bk0, z, 0,0,0);
            s[j]    = __builtin_amdgcn_mfma_f32_16x16x32_f16(aq1, bk1, t, 0,0,0);
        }
        // per-row bound early-out: chunk can contribute only if some row r has
        // max_j s[j][r]*al2 + lq9[r] > -1 (same monotone argument as the mask,
        // but with the row's own lq9 — tighter than the wave-level bound).
        float rmax[4];
        #pragma unroll
        for (int r=0;r<4;r++)
            rmax[r] = fmaxf(fmaxf(s[0][r], s[1][r]), fmaxf(s[2][r], s[3][r]));
        float rb = fmaxf(fmaxf(fmaf(rmax[0], al2, lq9[0]), fmaf(rmax[1], al2, lq9[1])),
                         fmaxf(fmaf(rmax[2], al2, lq9[2]), fmaf(rmax[3], al2, lq9[3])));
        if (!__ballot(rb > -1.0001f)) continue;

        float av[4][4];
        float amax = 0.f;
        #pragma unroll
        for (int j=0;j<4;j++){
            #pragma unroll
            for (int r=0;r<4;r++){
                float p1i = rintf(fminf(fexp2(fmaf(s[j][r], al2, lq9[r])), 255.f));
                float a   = rintf(fminf(p1i*r910, 127.f));
                av[j][r] = a;
                amax = fmaxf(amax, a);
            }
        }
        if (__ballot(amax > 0.f)){           // bound not tight: exact re-check
            #pragma unroll
            for (int j=0;j<4;j++)
                #pragma unroll
                for (int r=0;r<4;r++)
                    p16[w][quad*4+r][j*16+l15] = (_Float16)av[j][r];
            half8 ap0 = *(const half8*)(&p16[w][l15][quad*8]);
            half8 ap1 = *(const half8*)(&p16[w][l15][32+quad*8]);
            #pragma unroll
            for (int dt=0; dt<4; dt++){
                const _Float16* vr0 = vbase + (dt*16+l15)*2048 + ch*64;
                half8 b0 = *(const half8*)(vr0 + quad*8);
                half8 b1 = *(const half8*)(vr0 + 32 + quad*8);
                oacc[dt] = __builtin_amdgcn_mfma_f32_16x16x32_f16(ap0, b0, oacc[dt], 0,0,0);
                oacc[dt] = __builtin_amdgcn_mfma_f32_16x16x32_f16(ap1, b1, oacc[dt], 0,0,0);
            }
        }
    }

    // ---- epilogue: quantize with sc12 -> int8 (exact integer) ----
    float s1011 = b2f(scu[10]) * b2f(scu[11]);
    float s12   = b2f(scu[12]);
    int b = bh>>3, h = bh&7;
    #pragma unroll
    for (int dt=0; dt<4; dt++){
        #pragma unroll
        for (int r=0;r<4;r++){
            float o = oacc[dt][r] * s1011;
            signed char v = (signed char)rintf(clampf(o/s12, -128.f, 127.f));
            o8[(b*2048 + q0 + quad*4 + r)*512 + h*64 + dt*16 + l15] = v;
        }
    }
}

// ---------------------------------------------------------------------------
// Output projection: M=8192, N=512, K=512, + bias, bf16 out. 64x64 tiles.
// R8: int8 operands + v_mfma_i32_16x16x64_i8 (exact — see k_gemm_qkv note).
__global__ __launch_bounds__(256) void k_gemm_out(
    const signed char* __restrict__ o8, const signed char* __restrict__ wo8,
    const unsigned short* __restrict__ bo, unsigned short* __restrict__ out,
    const unsigned short* __restrict__ scu)
{
    __shared__ __align__(16) signed char At[64][64];
    __shared__ __align__(16) signed char Bt[64][64];
    int tid = threadIdx.x;
    int m0 = blockIdx.x*64, n0 = blockIdx.y*64;
    int w = tid>>6, lane = tid&63, l15 = lane&15, quad = lane>>4;
    int wm = w>>1, wn = w&1;
    i32x4 z = {0,0,0,0};
    i32x4 acc[2][2];
    #pragma unroll
    for (int i=0;i<2;i++)
      #pragma unroll
      for (int j=0;j<2;j++) acc[i][j] = z;

    for (int k0=0; k0<512; k0+=64){
        {                                    // A: 64x64 bytes = 256 x 16B
            int row = tid>>2, col = (tid&3)*16;
            int ubase = (w*64)*16;
            gld_lds16(o8  + (m0+row)*512 + k0 + col, &At[0][0] + ubase);
        }
        {                                    // B: 64x64 bytes = 256 x 16B
            int row = tid>>2, col = (tid&3)*16;
            int ubase = (w*64)*16;
            gld_lds16(wo8 + (n0+row)*512 + k0 + col, &Bt[0][0] + ubase);
        }
        __syncthreads();
        i32x4 af[2], bf[2];
        #pragma unroll
        for (int mt=0; mt<2; mt++)
            af[mt] = *(const i32x4*)(&At[wm*32+mt*16+l15][quad*16]);
        #pragma unroll
        for (int nt=0; nt<2; nt++)
            bf[nt] = *(const i32x4*)(&Bt[wn*32+nt*16+l15][quad*16]);
        #pragma unroll
        for (int mt=0; mt<2; mt++)
          #pragma unroll
          for (int nt=0; nt<2; nt++)
            acc[mt][nt] = __builtin_amdgcn_mfma_i32_16x16x64_i8(af[mt], bf[nt], acc[mt][nt], 0,0,0);
        __syncthreads();
    }

    float ssc = b2f(scu[12]) * b2f(scu[13]);
    #pragma unroll
    for (int mt=0; mt<2; mt++){
      #pragma unroll
      for (int nt=0; nt<2; nt++){
        int n = n0 + wn*32 + nt*16 + l15;
        float bn = b2f(bo[n]);
        #pragma unroll
        for (int r=0;r<4;r++){
          int m = m0 + wm*32 + mt*16 + quad*4 + r;
          out[m*512 + n] = f2b((float)acc[mt][nt][r]*ssc + bn);
        }
      }
    }
}

// ---------------------------------------------------------------------------
extern "C" void kernel_launch(void* const* d_in, const int* in_sizes, int n_in,
                              void* d_out, int out_size, void* d_ws, size_t ws_size,
                              hipStream_t stream)
{
    const unsigned short* hs = (const unsigned short*)d_in[0];
    const unsigned short* Wq = (const unsigned short*)d_in[1];
    const unsigned short* Wk = (const unsigned short*)d_in[2];
    const unsigned short* Wv = (const unsigned short*)d_in[3];
    const unsigned short* Wo = (const unsigned short*)d_in[4];
    const unsigned short* bo = (const unsigned short*)d_in[5];
    const unsigned short* sc = (const unsigned short*)d_in[6];
    unsigned short* out = (unsigned short*)d_out;

    unsigned char* ws = (unsigned char*)d_ws;
    signed char* w_all = (signed char*)(ws + BW_WALL);
    signed char* wo8   = (signed char*)(ws + BW_WO);
    signed char* a_q   = (signed char*)(ws + BW_AQ);
    signed char* a_k   = (signed char*)(ws + BW_AK);
    signed char* a_v   = (signed char*)(ws + BW_AV);
    _Float16*    q16   = (_Float16*)(ws + BW_Q);
    _Float16*    k16   = (_Float16*)(ws + BW_K);
    _Float16*    vt16  = (_Float16*)(ws + BW_VT);
    signed char* o8    = (signed char*)(ws + BW_O);

    k_quant<<<2560, 256, 0, stream>>>(hs, Wq, Wk, Wv, Wo, w_all, wo8,
                                      a_q, a_k, a_v, sc);
    k_gemm_qkv<<<dim3(64,24), 256, 0, stream>>>(a_q, a_k, a_v, w_all, q16, k16, vt16, sc);
    k_attn<<<dim3(32,16), 512, 0, stream>>>(q16, k16, vt16, o8, sc);
    k_gemm_out<<<dim3(128,8), 256, 0, stream>>>(o8, wo8, bo, out, sc);
}

// Round 9
// 141.704 us; speedup vs baseline: 1.1011x; 1.0195x over previous
//
#include <hip/hip_runtime.h>

typedef _Float16 half8  __attribute__((ext_vector_type(8)));
typedef float    f32x4  __attribute__((ext_vector_type(4)));
typedef int      i32x4  __attribute__((ext_vector_type(4)));
typedef unsigned short ushort8 __attribute__((ext_vector_type(8)));
typedef signed char char8 __attribute__((ext_vector_type(8)));

__device__ __forceinline__ float clampf(float v, float lo, float hi){
    return fminf(fmaxf(v, lo), hi);
}
__device__ __forceinline__ float b2f(unsigned short u){
    unsigned int x = ((unsigned int)u) << 16;
    return __builtin_bit_cast(float, x);
}
__device__ __forceinline__ unsigned short f2b(float f){
    unsigned int u = __builtin_bit_cast(unsigned int, f);
    u += 0x7FFFu + ((u >> 16) & 1u);       // round-to-nearest-even
    return (unsigned short)(u >> 16);
}
// raw v_exp_f32 (args bounded |x|<=~80 -> OCML safe path unnecessary)
__device__ __forceinline__ float fexp2(float x){ return __builtin_amdgcn_exp2f(x); }

// async global->LDS staging, 16B/lane.
__device__ __forceinline__ void gld_lds16(const void* g, void* lds_uniform){
    __builtin_amdgcn_global_load_lds(
        (const __attribute__((address_space(1))) void*)g,
        (__attribute__((address_space(3))) void*)lds_uniform, 16, 0, 0);
}

// ---------------------------------------------------------------------------
// ws layout in BYTES. R8: GEMM tensors int8. R9: attn tensors also int8
// (q8/k8/vt8) — all values are exact small integers.
#define BW_WALL 0u                        // [1536][512] i8 packed Wq/Wk/Wv rows
#define BW_WO   786432u                   // [512][512] i8
#define BW_AQ   1048576u                  // [8192][512] i8
#define BW_AK   (BW_AQ + 4194304u)
#define BW_AV   (BW_AK + 4194304u)
#define BW_Q    (BW_AV + 4194304u)        // i8 [bh=32][s=2048][d=64]
#define BW_K    (BW_Q  + 4194304u)
#define BW_VT   (BW_K  + 4194304u)        // i8 [bh][d=64][s=2048]
#define BW_O    (BW_VT + 4194304u)        // [8192][512] i8
// total = 30,408,704 bytes

// ---------------------------------------------------------------------------
// Merged quantization -> int8 outputs (R8: GEMMs run i8 MFMA).
__global__ __launch_bounds__(256) void k_quant(
    const unsigned short* __restrict__ hs,
    const unsigned short* __restrict__ Wq, const unsigned short* __restrict__ Wk,
    const unsigned short* __restrict__ Wv, const unsigned short* __restrict__ Wo,
    signed char* __restrict__ w_all, signed char* __restrict__ wo8,
    signed char* __restrict__ aq, signed char* __restrict__ ak,
    signed char* __restrict__ av,
    const unsigned short* __restrict__ scu)
{
    int blk = blockIdx.x;
    if (blk < 512){
        int gid  = blk * 256 + threadIdx.x;          // 131072 threads, 8 elems
        int idx8 = gid * 8;
        int which = idx8 >> 18;                      // 262144 elems per matrix
        int rem   = idx8 & 262143;
        const unsigned short* W = (which==0)? Wq : (which==1)? Wk : (which==2)? Wv : Wo;
        float sw = b2f((which<3) ? scu[2 + 2*which] : scu[13]);
        ushort8 w = *(const ushort8*)(W + rem);
        char8 o;
        #pragma unroll
        for (int j=0;j<8;j++)
            o[j] = (signed char)rintf(clampf(b2f(w[j])/sw, -128.f, 127.f));
        signed char* dst = (which<3) ? (w_all + which*262144 + rem) : (wo8 + rem);
        *(char8*)dst = o;
    } else {
        int gid = (blk - 512) * 256 + threadIdx.x;   // 524288 threads, 8 elems
        int i8 = gid * 8;
        float s0 = b2f(scu[0]), s1 = b2f(scu[1]), s3 = b2f(scu[3]), s5 = b2f(scu[5]);
        ushort8 h = *(const ushort8*)(hs + i8);
        char8 q, k, v;
        #pragma unroll
        for (int j=0;j<8;j++){
            float h1 = rintf(clampf(b2f(h[j])/s0, -128.f, 127.f)) * s0;  // fq(hs,s0)
            q[j] = (signed char)rintf(clampf(h1/s1, -128.f, 127.f));
            k[j] = (signed char)rintf(clampf(h1/s3, -128.f, 127.f));
            v[j] = (signed char)rintf(clampf(h1/s5, -128.f, 127.f));
        }
        *(char8*)(aq+i8) = q;
        *(char8*)(ak+i8) = k;
        *(char8*)(av+i8) = v;
    }
}

// ---------------------------------------------------------------------------
// QKV projection: M=8192, N=1536, K=512. 128x64 tiles, grid (64,24) = 1536
// blocks = 6 blocks/CU. R8: i8 operands + v_mfma_i32_16x16x64_i8 (exact).
// R9: epilogue emits q8/k8/vt8 as int8 (attn now consumes i8).
// R4 lesson stands: 128x64 @ 6 blocks/CU for this short-K shape.
__global__ __launch_bounds__(256) void k_gemm_qkv(
    const signed char* __restrict__ aq, const signed char* __restrict__ ak,
    const signed char* __restrict__ av, const signed char* __restrict__ w_all,
    signed char* __restrict__ q8, signed char* __restrict__ k8,
    signed char* __restrict__ vt8,
    const unsigned short* __restrict__ scu)
{
    __shared__ __align__(16) union SMem {
        struct { signed char At[128][64]; signed char Bt[64][64]; } ab;
        signed char Vt[64][144];         // row pad to 144B: 16B-aligned rows
    } sm;
    int tid = threadIdx.x;
    int m0 = blockIdx.x*128, n0 = blockIdx.y*64;
    int proj = blockIdx.y >> 3;                  // 8 n-blocks of 64 per projection
    const signed char* Ag = (proj==0)? aq : (proj==1)? ak : av;
    int w = tid>>6, lane = tid&63, l15 = lane&15, quad = lane>>4;
    int wm = w>>1, wn = w&1;
    i32x4 z = {0,0,0,0};
    i32x4 acc[4][2];
    #pragma unroll
    for (int i=0;i<4;i++)
      #pragma unroll
      for (int j=0;j<2;j++) acc[i][j] = z;

    for (int k0=0; k0<512; k0+=64){
        #pragma unroll
        for (int it=0; it<2; it++){          // A: 128x64 bytes = 512 x 16B
            int idx = it*256 + tid;
            int row = idx>>2, col = (idx&3)*16;
            int ubase = (it*256 + w*64)*16;  // wave-uniform LDS byte offset
            gld_lds16(Ag + (m0+row)*512 + k0 + col, &sm.ab.At[0][0] + ubase);
        }
        {                                    // B: 64x64 bytes = 256 x 16B
            int row = tid>>2, col = (tid&3)*16;
            int ubase = (w*64)*16;
            gld_lds16(w_all + (n0+row)*512 + k0 + col, &sm.ab.Bt[0][0] + ubase);
        }
        __syncthreads();
        i32x4 af[4], bf[2];
        #pragma unroll
        for (int mt=0; mt<4; mt++)
            af[mt] = *(const i32x4*)(&sm.ab.At[wm*64+mt*16+l15][quad*16]);
        #pragma unroll
        for (int nt=0; nt<2; nt++)
            bf[nt] = *(const i32x4*)(&sm.ab.Bt[wn*32+nt*16+l15][quad*16]);
        #pragma unroll
        for (int mt=0; mt<4; mt++)
          #pragma unroll
          for (int nt=0; nt<2; nt++)
            acc[mt][nt] = __builtin_amdgcn_mfma_i32_16x16x64_i8(af[mt], bf[nt], acc[mt][nt], 0,0,0);
        __syncthreads();
    }

    float ssc = b2f(scu[1+2*proj]) * b2f(scu[2+2*proj]);
    float qs  = b2f((proj==0)? scu[7] : (proj==1)? scu[8] : scu[11]);
    if (proj < 2){
        #pragma unroll
        for (int mt=0; mt<4; mt++){
          #pragma unroll
          for (int nt=0; nt<2; nt++){
            int n = n0 + wn*32 + nt*16 + l15;        // C/D col = lane&15 (verified)
            int nloc = n & 511;
            int h = nloc>>6, d = nloc&63;
            #pragma unroll
            for (int r=0;r<4;r++){
              int m = m0 + wm*64 + mt*16 + quad*4 + r;   // C/D row = quad*4+reg
              int b = m>>11, s = m&2047;
              int bh = b*8 + h;
              float val = (float)acc[mt][nt][r] * ssc;
              signed char qv = (signed char)rintf(clampf(val/qs, -128.f, 127.f));
              if (proj==0) q8[(bh*2048 + s)*64 + d] = qv;
              else         k8[(bh*2048 + s)*64 + d] = qv;
            }
          }
        }
    } else {
        // stage quantized V-tile into LDS transposed: Vt[n_local][m_local]
        #pragma unroll
        for (int mt=0; mt<4; mt++){
          #pragma unroll
          for (int nt=0; nt<2; nt++){
            int nl = wn*32 + nt*16 + l15;            // n-local 0..63
            #pragma unroll
            for (int r=0;r<4;r++){
              int ml = wm*64 + mt*16 + quad*4 + r;   // m-local 0..127
              float val = (float)acc[mt][nt][r] * ssc;
              sm.Vt[nl][ml] = (signed char)rintf(clampf(val/qs, -128.f, 127.f));
            }
          }
        }
        __syncthreads();
        int vrow = tid >> 2;                 // 0..63 (n-local)
        int vcol = (tid & 3) * 32;           // m-local base (32B per thread)
        int nloc2 = (n0 & 511) + vrow;
        int h2 = nloc2 >> 6, d2 = nloc2 & 63;
        int bh2 = (m0 >> 11)*8 + h2;
        int s2 = (m0 & 2047) + vcol;
        signed char* dst = vt8 + (bh2*64 + d2)*2048 + s2;
        *(i32x4*)(dst)      = *(const i32x4*)(&sm.Vt[vrow][vcol]);
        *(i32x4*)(dst + 16) = *(const i32x4*)(&sm.Vt[vrow][vcol + 16]);
    }
}

// ---------------------------------------------------------------------------
// Fused attention (R7 structure: 8 waves / 128 q-rows, grid (32,16)).
// R9: full int8 path. Q/K/V^T stored int8; QK^T = ONE mfma_i32_16x16x64_i8
// per 16-K-block (was 2 f16 K=32 mfmas); scores |s|<=2^20 < 2^24 so the
// i32->f32 convert is exact == old f32-MFMA scores, exp2/mask chain
// untouched. PV: P staged int8, V int8, i32 accumulation (exact; old f32
// path matched f32 reference exactly => identical). Staging: chunk = 4 KB,
// 8 B/thread; Kbuf rows padded to 80 B (16B-aligned, 2-way-max banks).
// Lessons ledger: R2 staging removal REVERTED (2.7x); R5 dist-2 prefetch
// REVERTED (neutral); R3 VALU diet kept; R6 XCD locality kept; R7 8-wave
// staging kept; R0/R16: (...,4) launch-bounds floor.
__global__ __launch_bounds__(512, 4) void k_attn(
    const signed char* __restrict__ q8, const signed char* __restrict__ k8,
    const signed char* __restrict__ vt8, signed char* __restrict__ o8,
    const unsigned short* __restrict__ scu)
{
    __shared__ __align__(16) signed char Kbuf[2][64][80];  // 64B data + 16B pad
    __shared__ __align__(16) signed char p8s[8][16][80];   // per-wave P staging
    int tid = threadIdx.x;
    int w = tid>>6, lane = tid&63, l15 = lane&15, quad = lane>>4;
    int bh = blockIdx.x;                     // XCD = bh%8 (R6)
    int q0 = blockIdx.y*128 + w*16;          // 8 waves cover 128 q-rows
    float s9 = b2f(scu[9]), s10 = b2f(scu[10]);
    float al2 = b2f(scu[7]) * b2f(scu[8]) * 0.125f * 1.44269504088896341f;

    i32x4 zi = {0,0,0,0};
    const signed char* qr = q8 + (bh*2048 + q0 + l15)*64;
    i32x4 aqf = *(const i32x4*)(qr + quad*16);   // Q row l15, K bytes quad*16..+15

    const signed char* kg    = k8  + bh*131072;
    const signed char* vbase = vt8 + bh*131072;
    int srow = tid>>3, scol = (tid&7)*8;     // 512 thr x 8B = one 4 KB chunk

    char8 kst = *(const char8*)(kg + tid*8); // chunk 0

    float l[4] = {0.f, 0.f, 0.f, 0.f};
    float cmx[32];                           // per-chunk per-lane max raw score

    // ---- pass 1: denominator sums + per-chunk maxima (UNROLLED: cmx regs) ----
    #pragma unroll
    for (int ch=0; ch<32; ch++){
        int buf = ch & 1;
        *(char8*)(&Kbuf[buf][srow][scol]) = kst;
        __syncthreads();
        if (ch < 31)                         // distance-1 prefetch after barrier
            kst = *(const char8*)(kg + (ch+1)*4096 + tid*8);
        float s[4][4];
        #pragma unroll
        for (int j=0;j<4;j++){
            i32x4 bk = *(const i32x4*)(&Kbuf[buf][j*16+l15][quad*16]);
            i32x4 si = __builtin_amdgcn_mfma_i32_16x16x64_i8(aqf, bk, zi, 0,0,0);
            #pragma unroll
            for (int r=0;r<4;r++) s[j][r] = (float)si[r];   // exact (<2^24)
        }
        // tree-max (v_max3-fusable), shallow dependency chain
        float mj[4];
        #pragma unroll
        for (int j=0;j<4;j++){
            mj[j] = fmaxf(fmaxf(s[j][0], s[j][1]), fmaxf(s[j][2], s[j][3]));
            #pragma unroll
            for (int r=0;r<4;r++)
                l[r] += fexp2(s[j][r]*al2);
        }
        cmx[ch] = fmaxf(fmaxf(mj[0], mj[1]), fmaxf(mj[2], mj[3]));
    }

    #pragma unroll
    for (int r=0;r<4;r++){
        #pragma unroll
        for (int d=1; d<16; d<<=1)
            l[r] += __shfl_xor(l[r], d, 64);
    }
    float inv_s9 = 1.0f / s9;
    float r910   = s9 / s10;
    float lq9[4];
    #pragma unroll
    for (int r=0;r<4;r++) lq9[r] = log2f(inv_s9 / l[r]);
    // per-lane threshold: max of THIS lane's rows' lq9 (no shuffles; tighter
    // than wave-max since a lane's scores pair only with its rows)
    float lml = fmaxf(fmaxf(lq9[0], lq9[1]), fmaxf(lq9[2], lq9[3]));
    // per-chunk needed mask: any-lane-over-threshold (ballot)
    unsigned int mask = 0u;
    #pragma unroll
    for (int ch=0; ch<32; ch++){
        if (__ballot(fmaf(cmx[ch], al2, lml) > -1.0001f)) mask |= (1u << ch);
    }

    // ---- pass 2: only masked chunks; direct global K loads; no barriers ----
    i32x4 oacc[4];
    #pragma unroll
    for (int dt=0; dt<4; dt++) oacc[dt] = zi;
    for (int ch=0; ch<32; ch++){
        if (!(mask & (1u << ch))) continue;
        const signed char* kc = kg + ch*4096;
        float s[4][4];
        #pragma unroll
        for (int j=0;j<4;j++){
            const signed char* kr = kc + (j*16+l15)*64;
            i32x4 bk = *(const i32x4*)(kr + quad*16);
            i32x4 si = __builtin_amdgcn_mfma_i32_16x16x64_i8(aqf, bk, zi, 0,0,0);
            #pragma unroll
            for (int r=0;r<4;r++) s[j][r] = (float)si[r];
        }
        // per-row bound early-out: chunk can contribute only if some row r has
        // max_j s[j][r]*al2 + lq9[r] > -1 (same monotone argument as the mask,
        // but with the row's own lq9 — tighter than the wave-level bound).
        float rmax[4];
        #pragma unroll
        for (int r=0;r<4;r++)
            rmax[r] = fmaxf(fmaxf(s[0][r], s[1][r]), fmaxf(s[2][r], s[3][r]));
        float rb = fmaxf(fmaxf(fmaf(rmax[0], al2, lq9[0]), fmaf(rmax[1], al2, lq9[1])),
                         fmaxf(fmaf(rmax[2], al2, lq9[2]), fmaf(rmax[3], al2, lq9[3])));
        if (!__ballot(rb > -1.0001f)) continue;

        float av[4][4];
        float amax = 0.f;
        #pragma unroll
        for (int j=0;j<4;j++){
            #pragma unroll
            for (int r=0;r<4;r++){
                float p1i = rintf(fminf(fexp2(fmaf(s[j][r], al2, lq9[r])), 255.f));
                float a   = rintf(fminf(p1i*r910, 127.f));
                av[j][r] = a;
                amax = fmaxf(amax, a);
            }
        }
        if (__ballot(amax > 0.f)){           // bound not tight: exact re-check
            #pragma unroll
            for (int j=0;j<4;j++)
                #pragma unroll
                for (int r=0;r<4;r++)
                    p8s[w][quad*4+r][j*16+l15] = (signed char)av[j][r];
            i32x4 ap = *(const i32x4*)(&p8s[w][l15][quad*16]);
            #pragma unroll
            for (int dt=0; dt<4; dt++){
                const signed char* vr0 = vbase + (dt*16+l15)*2048 + ch*64;
                i32x4 bv = *(const i32x4*)(vr0 + quad*16);
                oacc[dt] = __builtin_amdgcn_mfma_i32_16x16x64_i8(ap, bv, oacc[dt], 0,0,0);
            }
        }
    }

    // ---- epilogue: quantize with sc12 -> int8 (exact integer) ----
    float s1011 = b2f(scu[10]) * b2f(scu[11]);
    float s12   = b2f(scu[12]);
    int b = bh>>3, h = bh&7;
    #pragma unroll
    for (int dt=0; dt<4; dt++){
        #pragma unroll
        for (int r=0;r<4;r++){
            float o = (float)oacc[dt][r] * s1011;
            signed char v = (signed char)rintf(clampf(o/s12, -128.f, 127.f));
            o8[(b*2048 + q0 + quad*4 + r)*512 + h*64 + dt*16 + l15] = v;
        }
    }
}

// ---------------------------------------------------------------------------
// Output projection: M=8192, N=512, K=512, + bias, bf16 out. 64x64 tiles.
// R8: int8 operands + v_mfma_i32_16x16x64_i8 (exact — see k_gemm_qkv note).
__global__ __launch_bounds__(256) void k_gemm_out(
    const signed char* __restrict__ o8, const signed char* __restrict__ wo8,
    const unsigned short* __restrict__ bo, unsigned short* __restrict__ out,
    const unsigned short* __restrict__ scu)
{
    __shared__ __align__(16) signed char At[64][64];
    __shared__ __align__(16) signed char Bt[64][64];
    int tid = threadIdx.x;
    int m0 = blockIdx.x*64, n0 = blockIdx.y*64;
    int w = tid>>6, lane = tid&63, l15 = lane&15, quad = lane>>4;
    int wm = w>>1, wn = w&1;
    i32x4 z = {0,0,0,0};
    i32x4 acc[2][2];
    #pragma unroll
    for (int i=0;i<2;i++)
      #pragma unroll
      for (int j=0;j<2;j++) acc[i][j] = z;

    for (int k0=0; k0<512; k0+=64){
        {                                    // A: 64x64 bytes = 256 x 16B
            int row = tid>>2, col = (tid&3)*16;
            int ubase = (w*64)*16;
            gld_lds16(o8  + (m0+row)*512 + k0 + col, &At[0][0] + ubase);
        }
        {                                    // B: 64x64 bytes = 256 x 16B
            int row = tid>>2, col = (tid&3)*16;
            int ubase = (w*64)*16;
            gld_lds16(wo8 + (n0+row)*512 + k0 + col, &Bt[0][0] + ubase);
        }
        __syncthreads();
        i32x4 af[2], bf[2];
        #pragma unroll
        for (int mt=0; mt<2; mt++)
            af[mt] = *(const i32x4*)(&At[wm*32+mt*16+l15][quad*16]);
        #pragma unroll
        for (int nt=0; nt<2; nt++)
            bf[nt] = *(const i32x4*)(&Bt[wn*32+nt*16+l15][quad*16]);
        #pragma unroll
        for (int mt=0; mt<2; mt++)
          #pragma unroll
          for (int nt=0; nt<2; nt++)
            acc[mt][nt] = __builtin_amdgcn_mfma_i32_16x16x64_i8(af[mt], bf[nt], acc[mt][nt], 0,0,0);
        __syncthreads();
    }

    float ssc = b2f(scu[12]) * b2f(scu[13]);
    #pragma unroll
    for (int mt=0; mt<2; mt++){
      #pragma unroll
      for (int nt=0; nt<2; nt++){
        int n = n0 + wn*32 + nt*16 + l15;
        float bn = b2f(bo[n]);
        #pragma unroll
        for (int r=0;r<4;r++){
          int m = m0 + wm*32 + mt*16 + quad*4 + r;
          out[m*512 + n] = f2b((float)acc[mt][nt][r]*ssc + bn);
        }
      }
    }
}

// ---------------------------------------------------------------------------
extern "C" void kernel_launch(void* const* d_in, const int* in_sizes, int n_in,
                              void* d_out, int out_size, void* d_ws, size_t ws_size,
                              hipStream_t stream)
{
    const unsigned short* hs = (const unsigned short*)d_in[0];
    const unsigned short* Wq = (const unsigned short*)d_in[1];
    const unsigned short* Wk = (const unsigned short*)d_in[2];
    const unsigned short* Wv = (const unsigned short*)d_in[3];
    const unsigned short* Wo = (const unsigned short*)d_in[4];
    const unsigned short* bo = (const unsigned short*)d_in[5];
    const unsigned short* sc = (const unsigned short*)d_in[6];
    unsigned short* out = (unsigned short*)d_out;

    unsigned char* ws = (unsigned char*)d_ws;
    signed char* w_all = (signed char*)(ws + BW_WALL);
    signed char* wo8   = (signed char*)(ws + BW_WO);
    signed char* a_q   = (signed char*)(ws + BW_AQ);
    signed char* a_k   = (signed char*)(ws + BW_AK);
    signed char* a_v   = (signed char*)(ws + BW_AV);
    signed char* q8    = (signed char*)(ws + BW_Q);
    signed char* k8    = (signed char*)(ws + BW_K);
    signed char* vt8   = (signed char*)(ws + BW_VT);
    signed char* o8    = (signed char*)(ws + BW_O);

    k_quant<<<2560, 256, 0, stream>>>(hs, Wq, Wk, Wv, Wo, w_all, wo8,
                                      a_q, a_k, a_v, sc);
    k_gemm_qkv<<<dim3(64,24), 256, 0, stream>>>(a_q, a_k, a_v, w_all, q8, k8, vt8, sc);
    k_attn<<<dim3(32,16), 512, 0, stream>>>(q8, k8, vt8, o8, sc);
    k_gemm_out<<<dim3(128,8), 256, 0, stream>>>(o8, wo8, bo, out, sc);
}

// Round 10
// 140.201 us; speedup vs baseline: 1.1129x; 1.0107x over previous
//
#include <hip/hip_runtime.h>

typedef _Float16 half8  __attribute__((ext_vector_type(8)));
typedef float    f32x4  __attribute__((ext_vector_type(4)));
typedef int      i32x4  __attribute__((ext_vector_type(4)));
typedef unsigned short ushort8 __attribute__((ext_vector_type(8)));
typedef signed char char8 __attribute__((ext_vector_type(8)));

__device__ __forceinline__ float clampf(float v, float lo, float hi){
    return fminf(fmaxf(v, lo), hi);
}
__device__ __forceinline__ float b2f(unsigned short u){
    unsigned int x = ((unsigned int)u) << 16;
    return __builtin_bit_cast(float, x);
}
__device__ __forceinline__ unsigned short f2b(float f){
    unsigned int u = __builtin_bit_cast(unsigned int, f);
    u += 0x7FFFu + ((u >> 16) & 1u);       // round-to-nearest-even
    return (unsigned short)(u >> 16);
}
// raw v_exp_f32 (args bounded |x|<=~80 -> OCML safe path unnecessary)
__device__ __forceinline__ float fexp2(float x){ return __builtin_amdgcn_exp2f(x); }

// async global->LDS staging, 16B/lane.
__device__ __forceinline__ void gld_lds16(const void* g, void* lds_uniform){
    __builtin_amdgcn_global_load_lds(
        (const __attribute__((address_space(1))) void*)g,
        (__attribute__((address_space(3))) void*)lds_uniform, 16, 0, 0);
}

// ---------------------------------------------------------------------------
// ws layout in BYTES. All working tensors int8 (R8/R9).
#define BW_WALL 0u                        // [1536][512] i8 packed Wq/Wk/Wv rows
#define BW_WO   786432u                   // [512][512] i8
#define BW_AQ   1048576u                  // [8192][512] i8
#define BW_AK   (BW_AQ + 4194304u)
#define BW_AV   (BW_AK + 4194304u)
#define BW_Q    (BW_AV + 4194304u)        // i8 [bh=32][s=2048][d=64]
#define BW_K    (BW_Q  + 4194304u)
#define BW_VT   (BW_K  + 4194304u)        // i8 [bh][d=64][s=2048]
#define BW_O    (BW_VT + 4194304u)        // [8192][512] i8
// total = 30,408,704 bytes

// ---------------------------------------------------------------------------
// Merged quantization -> int8. R10: exact scale-equality strength reduction.
//  hq = rint(clamp(hs/s0)); h1 = hq*s0 (EXACT: 15-bit product).
//  If s1==s0 (bit-equal): (hq*s0)/s1 == hq exactly (IEEE: exact quotient is
//  representable) -> a_q = hq, NO division. If s3==s1: a_k tensor is
//  element-wise identical to a_q -> skip writing it (qkv reads aq instead).
//  Branches are wave-uniform (scales); slow path bit-identical to before.
__global__ __launch_bounds__(256) void k_quant(
    const unsigned short* __restrict__ hs,
    const unsigned short* __restrict__ Wq, const unsigned short* __restrict__ Wk,
    const unsigned short* __restrict__ Wv, const unsigned short* __restrict__ Wo,
    signed char* __restrict__ w_all, signed char* __restrict__ wo8,
    signed char* __restrict__ aq, signed char* __restrict__ ak,
    signed char* __restrict__ av,
    const unsigned short* __restrict__ scu)
{
    int blk = blockIdx.x;
    if (blk < 512){
        int gid  = blk * 256 + threadIdx.x;          // 131072 threads, 8 elems
        int idx8 = gid * 8;
        int which = idx8 >> 18;                      // 262144 elems per matrix
        int rem   = idx8 & 262143;
        const unsigned short* W = (which==0)? Wq : (which==1)? Wk : (which==2)? Wv : Wo;
        float sw = b2f((which<3) ? scu[2 + 2*which] : scu[13]);
        ushort8 w = *(const ushort8*)(W + rem);
        char8 o;
        #pragma unroll
        for (int j=0;j<8;j++)
            o[j] = (signed char)rintf(clampf(b2f(w[j])/sw, -128.f, 127.f));
        signed char* dst = (which<3) ? (w_all + which*262144 + rem) : (wo8 + rem);
        *(char8*)dst = o;
    } else {
        int gid = (blk - 512) * 256 + threadIdx.x;   // 524288 threads, 8 elems
        int i8 = gid * 8;
        unsigned short u0=scu[0], u1=scu[1], u3=scu[3], u5=scu[5];
        float s0=b2f(u0), s1=b2f(u1), s3=b2f(u3), s5=b2f(u5);
        bool f1 = (u1==u0), f3 = (u3==u0), f5 = (u5==u0); // div-free fast path
        bool wK = (u3!=u1), wV = (u5!=u1);               // ak/av distinct from aq?
        ushort8 h = *(const ushort8*)(hs + i8);
        char8 q, k, v;
        #pragma unroll
        for (int j=0;j<8;j++){
            float hq = rintf(clampf(b2f(h[j])/s0, -128.f, 127.f));
            float h1 = hq * s0;                          // exact
            q[j] = f1 ? (signed char)hq
                      : (signed char)rintf(clampf(h1/s1, -128.f, 127.f));
            if (wK) k[j] = f3 ? (signed char)hq
                              : (signed char)rintf(clampf(h1/s3, -128.f, 127.f));
            if (wV) v[j] = f5 ? (signed char)hq
                              : (signed char)rintf(clampf(h1/s5, -128.f, 127.f));
        }
        *(char8*)(aq+i8) = q;
        if (wK) *(char8*)(ak+i8) = k;
        if (wV) *(char8*)(av+i8) = v;
    }
}

// ---------------------------------------------------------------------------
// QKV projection: M=8192, N=1536, K=512. 128x64 tiles, grid (64,24) = 1536
// blocks = 6 blocks/CU. R8: i8 + v_mfma_i32_16x16x64_i8 (exact).
// R10: A-pointer selected by scale equality (matches k_quant's dedup) —
// when s3==s1 / s5==s1 all projections read the single aq tensor (4 MB,
// L2-resident). R4 lesson stands: 128x64 @ 6 blocks/CU for short-K.
__global__ __launch_bounds__(256) void k_gemm_qkv(
    const signed char* __restrict__ aq, const signed char* __restrict__ ak,
    const signed char* __restrict__ av, const signed char* __restrict__ w_all,
    signed char* __restrict__ q8, signed char* __restrict__ k8,
    signed char* __restrict__ vt8,
    const unsigned short* __restrict__ scu)
{
    __shared__ __align__(16) union SMem {
        struct { signed char At[128][64]; signed char Bt[64][64]; } ab;
        signed char Vt[64][144];         // row pad to 144B: 16B-aligned rows
    } sm;
    int tid = threadIdx.x;
    int m0 = blockIdx.x*128, n0 = blockIdx.y*64;
    int proj = blockIdx.y >> 3;                  // 8 n-blocks of 64 per projection
    unsigned short u1=scu[1], u3=scu[3], u5=scu[5];
    const signed char* Ag = (proj==0)? aq
                          : (proj==1)? ((u3==u1)? aq : ak)
                                     : ((u5==u1)? aq : av);
    int w = tid>>6, lane = tid&63, l15 = lane&15, quad = lane>>4;
    int wm = w>>1, wn = w&1;
    i32x4 z = {0,0,0,0};
    i32x4 acc[4][2];
    #pragma unroll
    for (int i=0;i<4;i++)
      #pragma unroll
      for (int j=0;j<2;j++) acc[i][j] = z;

    for (int k0=0; k0<512; k0+=64){
        #pragma unroll
        for (int it=0; it<2; it++){          // A: 128x64 bytes = 512 x 16B
            int idx = it*256 + tid;
            int row = idx>>2, col = (idx&3)*16;
            int ubase = (it*256 + w*64)*16;  // wave-uniform LDS byte offset
            gld_lds16(Ag + (m0+row)*512 + k0 + col, &sm.ab.At[0][0] + ubase);
        }
        {                                    // B: 64x64 bytes = 256 x 16B
            int row = tid>>2, col = (tid&3)*16;
            int ubase = (w*64)*16;
            gld_lds16(w_all + (n0+row)*512 + k0 + col, &sm.ab.Bt[0][0] + ubase);
        }
        __syncthreads();
        i32x4 af[4], bf[2];
        #pragma unroll
        for (int mt=0; mt<4; mt++)
            af[mt] = *(const i32x4*)(&sm.ab.At[wm*64+mt*16+l15][quad*16]);
        #pragma unroll
        for (int nt=0; nt<2; nt++)
            bf[nt] = *(const i32x4*)(&sm.ab.Bt[wn*32+nt*16+l15][quad*16]);
        #pragma unroll
        for (int mt=0; mt<4; mt++)
          #pragma unroll
          for (int nt=0; nt<2; nt++)
            acc[mt][nt] = __builtin_amdgcn_mfma_i32_16x16x64_i8(af[mt], bf[nt], acc[mt][nt], 0,0,0);
        __syncthreads();
    }

    float ssc = b2f(scu[1+2*proj]) * b2f(scu[2+2*proj]);
    float qs  = b2f((proj==0)? scu[7] : (proj==1)? scu[8] : scu[11]);
    if (proj < 2){
        #pragma unroll
        for (int mt=0; mt<4; mt++){
          #pragma unroll
          for (int nt=0; nt<2; nt++){
            int n = n0 + wn*32 + nt*16 + l15;        // C/D col = lane&15 (verified)
            int nloc = n & 511;
            int h = nloc>>6, d = nloc&63;
            #pragma unroll
            for (int r=0;r<4;r++){
              int m = m0 + wm*64 + mt*16 + quad*4 + r;   // C/D row = quad*4+reg
              int b = m>>11, s = m&2047;
              int bh = b*8 + h;
              float val = (float)acc[mt][nt][r] * ssc;
              signed char qv = (signed char)rintf(clampf(val/qs, -128.f, 127.f));
              if (proj==0) q8[(bh*2048 + s)*64 + d] = qv;
              else         k8[(bh*2048 + s)*64 + d] = qv;
            }
          }
        }
    } else {
        // stage quantized V-tile into LDS transposed: Vt[n_local][m_local]
        #pragma unroll
        for (int mt=0; mt<4; mt++){
          #pragma unroll
          for (int nt=0; nt<2; nt++){
            int nl = wn*32 + nt*16 + l15;            // n-local 0..63
            #pragma unroll
            for (int r=0;r<4;r++){
              int ml = wm*64 + mt*16 + quad*4 + r;   // m-local 0..127
              float val = (float)acc[mt][nt][r] * ssc;
              sm.Vt[nl][ml] = (signed char)rintf(clampf(val/qs, -128.f, 127.f));
            }
          }
        }
        __syncthreads();
        int vrow = tid >> 2;                 // 0..63 (n-local)
        int vcol = (tid & 3) * 32;           // m-local base (32B per thread)
        int nloc2 = (n0 & 511) + vrow;
        int h2 = nloc2 >> 6, d2 = nloc2 & 63;
        int bh2 = (m0 >> 11)*8 + h2;
        int s2 = (m0 & 2047) + vcol;
        signed char* dst = vt8 + (bh2*64 + d2)*2048 + s2;
        *(i32x4*)(dst)      = *(const i32x4*)(&sm.Vt[vrow][vcol]);
        *(i32x4*)(dst + 16) = *(const i32x4*)(&sm.Vt[vrow][vcol + 16]);
    }
}

// ---------------------------------------------------------------------------
// Fused attention (R7 structure: 8 waves / 128 q-rows, grid (32,16)).
// R9: full int8 path — QK^T one mfma_i32_16x16x64_i8 per 16-K-block (scores
// <2^24: i32->f32 cvt exact), PV in i32 (exact). Kbuf 80B-padded rows.
// Lessons ledger: R2 staging removal REVERTED (2.7x); R5 dist-2 prefetch
// REVERTED (neutral); R3 VALU diet kept; R6 XCD locality kept; R7 8-wave
// staging kept; R0/R16: (...,4) launch-bounds floor.
__global__ __launch_bounds__(512, 4) void k_attn(
    const signed char* __restrict__ q8, const signed char* __restrict__ k8,
    const signed char* __restrict__ vt8, signed char* __restrict__ o8,
    const unsigned short* __restrict__ scu)
{
    __shared__ __align__(16) signed char Kbuf[2][64][80];  // 64B data + 16B pad
    __shared__ __align__(16) signed char p8s[8][16][80];   // per-wave P staging
    int tid = threadIdx.x;
    int w = tid>>6, lane = tid&63, l15 = lane&15, quad = lane>>4;
    int bh = blockIdx.x;                     // XCD = bh%8 (R6)
    int q0 = blockIdx.y*128 + w*16;          // 8 waves cover 128 q-rows
    float s9 = b2f(scu[9]), s10 = b2f(scu[10]);
    float al2 = b2f(scu[7]) * b2f(scu[8]) * 0.125f * 1.44269504088896341f;

    i32x4 zi = {0,0,0,0};
    const signed char* qr = q8 + (bh*2048 + q0 + l15)*64;
    i32x4 aqf = *(const i32x4*)(qr + quad*16);   // Q row l15, K bytes quad*16..+15

    const signed char* kg    = k8  + bh*131072;
    const signed char* vbase = vt8 + bh*131072;
    int srow = tid>>3, scol = (tid&7)*8;     // 512 thr x 8B = one 4 KB chunk

    char8 kst = *(const char8*)(kg + tid*8); // chunk 0

    float l[4] = {0.f, 0.f, 0.f, 0.f};
    float cmx[32];                           // per-chunk per-lane max raw score

    // ---- pass 1: denominator sums + per-chunk maxima (UNROLLED: cmx regs) ----
    #pragma unroll
    for (int ch=0; ch<32; ch++){
        int buf = ch & 1;
        *(char8*)(&Kbuf[buf][srow][scol]) = kst;
        __syncthreads();
        if (ch < 31)                         // distance-1 prefetch after barrier
            kst = *(const char8*)(kg + (ch+1)*4096 + tid*8);
        float s[4][4];
        #pragma unroll
        for (int j=0;j<4;j++){
            i32x4 bk = *(const i32x4*)(&Kbuf[buf][j*16+l15][quad*16]);
            i32x4 si = __builtin_amdgcn_mfma_i32_16x16x64_i8(aqf, bk, zi, 0,0,0);
            #pragma unroll
            for (int r=0;r<4;r++) s[j][r] = (float)si[r];   // exact (<2^24)
        }
        // tree-max (v_max3-fusable), shallow dependency chain
        float mj[4];
        #pragma unroll
        for (int j=0;j<4;j++){
            mj[j] = fmaxf(fmaxf(s[j][0], s[j][1]), fmaxf(s[j][2], s[j][3]));
            #pragma unroll
            for (int r=0;r<4;r++)
                l[r] += fexp2(s[j][r]*al2);
        }
        cmx[ch] = fmaxf(fmaxf(mj[0], mj[1]), fmaxf(mj[2], mj[3]));
    }

    #pragma unroll
    for (int r=0;r<4;r++){
        #pragma unroll
        for (int d=1; d<16; d<<=1)
            l[r] += __shfl_xor(l[r], d, 64);
    }
    float inv_s9 = 1.0f / s9;
    float r910   = s9 / s10;
    float lq9[4];
    #pragma unroll
    for (int r=0;r<4;r++) lq9[r] = log2f(inv_s9 / l[r]);
    // per-lane threshold: max of THIS lane's rows' lq9 (no shuffles; tighter
    // than wave-max since a lane's scores pair only with its rows)
    float lml = fmaxf(fmaxf(lq9[0], lq9[1]), fmaxf(lq9[2], lq9[3]));
    // per-chunk needed mask: any-lane-over-threshold (ballot)
    unsigned int mask = 0u;
    #pragma unroll
    for (int ch=0; ch<32; ch++){
        if (__ballot(fmaf(cmx[ch], al2, lml) > -1.0001f)) mask |= (1u << ch);
    }

    // ---- pass 2: only masked chunks; direct global K loads; no barriers ----
    i32x4 oacc[4];
    #pragma unroll
    for (int dt=0; dt<4; dt++) oacc[dt] = zi;
    for (int ch=0; ch<32; ch++){
        if (!(mask & (1u << ch))) continue;
        const signed char* kc = kg + ch*4096;
        float s[4][4];
        #pragma unroll
        for (int j=0;j<4;j++){
            const signed char* kr = kc + (j*16+l15)*64;
            i32x4 bk = *(const i32x4*)(kr + quad*16);
            i32x4 si = __builtin_amdgcn_mfma_i32_16x16x64_i8(aqf, bk, zi, 0,0,0);
            #pragma unroll
            for (int r=0;r<4;r++) s[j][r] = (float)si[r];
        }
        // per-row bound early-out: chunk can contribute only if some row r has
        // max_j s[j][r]*al2 + lq9[r] > -1 (same monotone argument as the mask,
        // but with the row's own lq9 — tighter than the wave-level bound).
        float rmax[4];
        #pragma unroll
        for (int r=0;r<4;r++)
            rmax[r] = fmaxf(fmaxf(s[0][r], s[1][r]), fmaxf(s[2][r], s[3][r]));
        float rb = fmaxf(fmaxf(fmaf(rmax[0], al2, lq9[0]), fmaf(rmax[1], al2, lq9[1])),
                         fmaxf(fmaf(rmax[2], al2, lq9[2]), fmaf(rmax[3], al2, lq9[3])));
        if (!__ballot(rb > -1.0001f)) continue;

        float av[4][4];
        float amax = 0.f;
        #pragma unroll
        for (int j=0;j<4;j++){
            #pragma unroll
            for (int r=0;r<4;r++){
                float p1i = rintf(fminf(fexp2(fmaf(s[j][r], al2, lq9[r])), 255.f));
                float a   = rintf(fminf(p1i*r910, 127.f));
                av[j][r] = a;
                amax = fmaxf(amax, a);
            }
        }
        if (__ballot(amax > 0.f)){           // bound not tight: exact re-check
            #pragma unroll
            for (int j=0;j<4;j++)
                #pragma unroll
                for (int r=0;r<4;r++)
                    p8s[w][quad*4+r][j*16+l15] = (signed char)av[j][r];
            i32x4 ap = *(const i32x4*)(&p8s[w][l15][quad*16]);
            #pragma unroll
            for (int dt=0; dt<4; dt++){
                const signed char* vr0 = vbase + (dt*16+l15)*2048 + ch*64;
                i32x4 bv = *(const i32x4*)(vr0 + quad*16);
                oacc[dt] = __builtin_amdgcn_mfma_i32_16x16x64_i8(ap, bv, oacc[dt], 0,0,0);
            }
        }
    }

    // ---- epilogue: quantize with sc12 -> int8 (exact integer) ----
    float s1011 = b2f(scu[10]) * b2f(scu[11]);
    float s12   = b2f(scu[12]);
    int b = bh>>3, h = bh&7;
    #pragma unroll
    for (int dt=0; dt<4; dt++){
        #pragma unroll
        for (int r=0;r<4;r++){
            float o = (float)oacc[dt][r] * s1011;
            signed char v = (signed char)rintf(clampf(o/s12, -128.f, 127.f));
            o8[(b*2048 + q0 + quad*4 + r)*512 + h*64 + dt*16 + l15] = v;
        }
    }
}

// ---------------------------------------------------------------------------
// Output projection: M=8192, N=512, K=512, + bias, bf16 out. 64x64 tiles.
// R8: int8 operands + v_mfma_i32_16x16x64_i8 (exact — see k_gemm_qkv note).
__global__ __launch_bounds__(256) void k_gemm_out(
    const signed char* __restrict__ o8, const signed char* __restrict__ wo8,
    const unsigned short* __restrict__ bo, unsigned short* __restrict__ out,
    const unsigned short* __restrict__ scu)
{
    __shared__ __align__(16) signed char At[64][64];
    __shared__ __align__(16) signed char Bt[64][64];
    int tid = threadIdx.x;
    int m0 = blockIdx.x*64, n0 = blockIdx.y*64;
    int w = tid>>6, lane = tid&63, l15 = lane&15, quad = lane>>4;
    int wm = w>>1, wn = w&1;
    i32x4 z = {0,0,0,0};
    i32x4 acc[2][2];
    #pragma unroll
    for (int i=0;i<2;i++)
      #pragma unroll
      for (int j=0;j<2;j++) acc[i][j] = z;

    for (int k0=0; k0<512; k0+=64){
        {                                    // A: 64x64 bytes = 256 x 16B
            int row = tid>>2, col = (tid&3)*16;
            int ubase = (w*64)*16;
            gld_lds16(o8  + (m0+row)*512 + k0 + col, &At[0][0] + ubase);
        }
        {                                    // B: 64x64 bytes = 256 x 16B
            int row = tid>>2, col = (tid&3)*16;
            int ubase = (w*64)*16;
            gld_lds16(wo8 + (n0+row)*512 + k0 + col, &Bt[0][0] + ubase);
        }
        __syncthreads();
        i32x4 af[2], bf[2];
        #pragma unroll
        for (int mt=0; mt<2; mt++)
            af[mt] = *(const i32x4*)(&At[wm*32+mt*16+l15][quad*16]);
        #pragma unroll
        for (int nt=0; nt<2; nt++)
            bf[nt] = *(const i32x4*)(&Bt[wn*32+nt*16+l15][quad*16]);
        #pragma unroll
        for (int mt=0; mt<2; mt++)
          #pragma unroll
          for (int nt=0; nt<2; nt++)
            acc[mt][nt] = __builtin_amdgcn_mfma_i32_16x16x64_i8(af[mt], bf[nt], acc[mt][nt], 0,0,0);
        __syncthreads();
    }

    float ssc = b2f(scu[12]) * b2f(scu[13]);
    #pragma unroll
    for (int mt=0; mt<2; mt++){
      #pragma unroll
      for (int nt=0; nt<2; nt++){
        int n = n0 + wn*32 + nt*16 + l15;
        float bn = b2f(bo[n]);
        #pragma unroll
        for (int r=0;r<4;r++){
          int m = m0 + wm*32 + mt*16 + quad*4 + r;
          out[m*512 + n] = f2b((float)acc[mt][nt][r]*ssc + bn);
        }
      }
    }
}

// ---------------------------------------------------------------------------
extern "C" void kernel_launch(void* const* d_in, const int* in_sizes, int n_in,
                              void* d_out, int out_size, void* d_ws, size_t ws_size,
                              hipStream_t stream)
{
    const unsigned short* hs = (const unsigned short*)d_in[0];
    const unsigned short* Wq = (const unsigned short*)d_in[1];
    const unsigned short* Wk = (const unsigned short*)d_in[2];
    const unsigned short* Wv = (const unsigned short*)d_in[3];
    const unsigned short* Wo = (const unsigned short*)d_in[4];
    const unsigned short* bo = (const unsigned short*)d_in[5];
    const unsigned short* sc = (const unsigned short*)d_in[6];
    unsigned short* out = (unsigned short*)d_out;

    unsigned char* ws = (unsigned char*)d_ws;
    signed char* w_all = (signed char*)(ws + BW_WALL);
    signed char* wo8   = (signed char*)(ws + BW_WO);
    signed char* a_q   = (signed char*)(ws + BW_AQ);
    signed char* a_k   = (signed char*)(ws + BW_AK);
    signed char* a_v   = (signed char*)(ws + BW_AV);
    signed char* q8    = (signed char*)(ws + BW_Q);
    signed char* k8    = (signed char*)(ws + BW_K);
    signed char* vt8   = (signed char*)(ws + BW_VT);
    signed char* o8    = (signed char*)(ws + BW_O);

    k_quant<<<2560, 256, 0, stream>>>(hs, Wq, Wk, Wv, Wo, w_all, wo8,
                                      a_q, a_k, a_v, sc);
    k_gemm_qkv<<<dim3(64,24), 256, 0, stream>>>(a_q, a_k, a_v, w_all, q8, k8, vt8, sc);
    k_attn<<<dim3(32,16), 512, 0, stream>>>(q8, k8, vt8, o8, sc);
    k_gemm_out<<<dim3(128,8), 256, 0, stream>>>(o8, wo8, bo, out, sc);
}